// Round 10
// baseline (346.287 us; speedup 1.0000x reference)
//
#include <hip/hip_runtime.h>

// Masked attention, b=8 n=m=4096 d=dv=64, f32 in/out.
// R10: R9 (QBLK=64/wave, halved VMEM — verified 73->59.7us) + 2x TLP:
// 512 thr / 8 waves / 8-way key split (8 tiles per wave). Same total VMEM;
// 4096 waves = 4 waves/SIMD (VGPR<=128 via launch_bounds(512,4); R9 body=116).

#define B_ 8
#define N_ 4096
#define M_ 4096
#define D_ 64

typedef __attribute__((ext_vector_type(8))) __bf16 bfrag;
typedef __attribute__((ext_vector_type(16))) float f32x16;
typedef __attribute__((ext_vector_type(4))) float f32x4;

union FragU { bfrag f; unsigned int u[4]; };

__device__ __forceinline__ unsigned int pkbf(float lo, float hi) {
  unsigned short a = __builtin_bit_cast(unsigned short, (__bf16)lo);
  unsigned short b = __builtin_bit_cast(unsigned short, (__bf16)hi);
  return ((unsigned int)b << 16) | (unsigned int)a;
}
__device__ __forceinline__ unsigned short bf1(float x) {
  return __builtin_bit_cast(unsigned short, (__bf16)x);
}

// ---------------- prepass: pack fragment-order bf16 images ----------------
__global__ void attn_prepass(const float* __restrict__ kg, const float* __restrict__ vg,
                             char* __restrict__ kpack, char* __restrict__ vpack)
{
  const int bid = blockIdx.x, tid = threadIdx.x;
  if (bid < 1024) {
    const unsigned c0 = bid * 256 + tid;     // 0..262143
    const int lane = c0 & 63;
    const unsigned u = c0 >> 6;
    const int f = u & 1, c = (u >> 1) & 3, tile = (u >> 3) & 63, batch = u >> 9;
    const int lq = lane & 31, lh = lane >> 5;
    const int row = tile * 64 + f * 32 + lq;
    const float* src = kg + (((size_t)batch * M_ + row) * D_ + c * 16 + lh * 8);
    float4 a = ((const float4*)src)[0], b = ((const float4*)src)[1];
    uint4 o;
    o.x = pkbf(a.x, a.y); o.y = pkbf(a.z, a.w);
    o.z = pkbf(b.x, b.y); o.w = pkbf(b.z, b.w);
    *(uint4*)(kpack + (size_t)c0 * 16) = o;
  } else {
    const unsigned c0 = (bid - 1024) * 256 + tid;
    const int lane = c0 & 63;
    const unsigned u = c0 >> 6;
    const int f = u & 1, mc = (u >> 1) & 3, tile = (u >> 3) & 63, batch = u >> 9;
    const int lq = lane & 31, lh = lane >> 5;
    const int key0 = tile * 64 + mc * 16 + lh * 8;
    const int dv = f * 32 + lq;
    const float* base = vg + (((size_t)batch * M_ + key0) * D_ + dv);
    unsigned short h[8];
#pragma unroll
    for (int j = 0; j < 8; ++j) h[j] = bf1(base[(size_t)j * D_]);
    uint4 o;
    o.x = (unsigned)h[0] | ((unsigned)h[1] << 16);
    o.y = (unsigned)h[2] | ((unsigned)h[3] << 16);
    o.z = (unsigned)h[4] | ((unsigned)h[5] << 16);
    o.w = (unsigned)h[6] | ((unsigned)h[7] << 16);
    *(uint4*)(vpack + (size_t)c0 * 16) = o;
  }
}

// ---------------- main kernel: 512 thr, 8-way key split, QBLK=64/wave --------
// LDS: loop: bias[4096] f32 in [0,16384)
//      epilogue: bufs[4][32][64] f32 = 32768 (reused for group A then B)
//      32768 lArrA[8][32]; 33792 lArrB[8][32]; 34816 IlvA[32]; 34944 IlvB[32]
__global__ __launch_bounds__(512, 4) void attn_main(
    const float* __restrict__ qg, const int* __restrict__ mqg,
    const int* __restrict__ mkg, const char* __restrict__ kpack,
    const char* __restrict__ vpack, float* __restrict__ outg)
{
  __shared__ alignas(16) char smem[35072];
  const int tid  = threadIdx.x;
  const int lane = tid & 63;
  const int lq   = lane & 31;
  const int lh   = lane >> 5;
  const int wid  = tid >> 6;            // key eighth, 0..7
  const int batch = blockIdx.x & 7;     // batch == XCD for L2 locality
  const int qbase = (blockIdx.x >> 3) * 64;

  float* lArrA = (float*)(smem + 32768);
  float* lArrB = (float*)(smem + 33792);
  float* IlvA  = (float*)(smem + 34816);
  float* IlvB  = (float*)(smem + 34944);

  // ---- stage key bias into LDS (cooperative, broadcast-read later) ----
  {
    const int4* mk4 = (const int4*)(mkg + batch * M_);
    float* bl = (float*)smem;
#pragma unroll
    for (int j = 0; j < 2; ++j) {
      const int i4 = tid + j * 512;
      int4 m4 = mk4[i4];
      f32x4 bv;
      bv[0] = m4.x ? 0.f : -1e30f;
      bv[1] = m4.y ? 0.f : -1e30f;
      bv[2] = m4.z ? 0.f : -1e30f;
      bv[3] = m4.w ? 0.f : -1e30f;
      *(f32x4*)(bl + i4 * 4) = bv;
    }
  }

  // ---- Q frags for both 32-row groups (A: rows +lq, B: rows +32+lq) ----
  bfrag qfA[4], qfB[4];
  {
    const int growA = qbase + lq;
    const float qsA = mqg[batch * N_ + growA] ? 0.1803368801111204f : 0.0f;
    const float* QpA = qg + ((size_t)batch * N_ + growA) * D_ + lh * 8;
#pragma unroll
    for (int c = 0; c < 4; ++c) {
      float4 a = *(const float4*)(QpA + c * 16);
      float4 b = *(const float4*)(QpA + c * 16 + 4);
      FragU f;
      f.u[0] = pkbf(a.x * qsA, a.y * qsA);
      f.u[1] = pkbf(a.z * qsA, a.w * qsA);
      f.u[2] = pkbf(b.x * qsA, b.y * qsA);
      f.u[3] = pkbf(b.z * qsA, b.w * qsA);
      qfA[c] = f.f;
    }
    const int growB = qbase + 32 + lq;
    const float qsB = mqg[batch * N_ + growB] ? 0.1803368801111204f : 0.0f;
    const float* QpB = qg + ((size_t)batch * N_ + growB) * D_ + lh * 8;
#pragma unroll
    for (int c = 0; c < 4; ++c) {
      float4 a = *(const float4*)(QpB + c * 16);
      float4 b = *(const float4*)(QpB + c * 16 + 4);
      FragU f;
      f.u[0] = pkbf(a.x * qsB, a.y * qsB);
      f.u[1] = pkbf(a.z * qsB, a.w * qsB);
      f.u[2] = pkbf(b.x * qsB, b.y * qsB);
      f.u[3] = pkbf(b.z * qsB, b.w * qsB);
      qfB[c] = f.f;
    }
  }
  __syncthreads();  // bias staged

  f32x16 oA0, oA1, oB0, oB1;
#pragma unroll
  for (int i = 0; i < 16; ++i) { oA0[i] = 0.f; oA1[i] = 0.f; oB0[i] = 0.f; oB1[i] = 0.f; }
  float lsumA = 0.f, lsumB = 0.f;

  const float* blw = (const float*)smem + wid * 512;

  for (int t8 = 0; t8 < 8; ++t8) {
    const int tile = wid * 8 + t8;
    const size_t tb = (size_t)(batch * 64 + tile) * 8192 + (size_t)lane * 16;

    // ---- K + V frags (one load set feeds both q-groups) ----
    bfrag kf[4][2];
#pragma unroll
    for (int c = 0; c < 4; ++c) {
      kf[c][0] = *(const bfrag*)(kpack + tb + (c * 2 + 0) * 1024);
      kf[c][1] = *(const bfrag*)(kpack + tb + (c * 2 + 1) * 1024);
    }
    bfrag vf[4][2];
#pragma unroll
    for (int mc = 0; mc < 4; ++mc) {
      vf[mc][0] = *(const bfrag*)(vpack + tb + (mc * 2 + 0) * 1024);
      vf[mc][1] = *(const bfrag*)(vpack + tb + (mc * 2 + 1) * 1024);
    }

    // ---- swapped QK^T for both groups ----
    f32x16 sA0, sA1, sB0, sB1;
#pragma unroll
    for (int i = 0; i < 16; ++i) { sA0[i] = 0.f; sA1[i] = 0.f; sB0[i] = 0.f; sB1[i] = 0.f; }
    __builtin_amdgcn_s_setprio(1);
#pragma unroll
    for (int c = 0; c < 4; ++c) {
      sA0 = __builtin_amdgcn_mfma_f32_32x32x16_bf16(kf[c][0], qfA[c], sA0, 0, 0, 0);
      sA1 = __builtin_amdgcn_mfma_f32_32x32x16_bf16(kf[c][1], qfA[c], sA1, 0, 0, 0);
      sB0 = __builtin_amdgcn_mfma_f32_32x32x16_bf16(kf[c][0], qfB[c], sB0, 0, 0, 0);
      sB1 = __builtin_amdgcn_mfma_f32_32x32x16_bf16(kf[c][1], qfB[c], sB1, 0, 0, 0);
    }
    __builtin_amdgcn_s_setprio(0);

    // ---- softmax numerators, both groups (bias shared; no max: R7) ----
    const float* bb = blw + t8 * 64;
    f32x4 psvA = {0.f, 0.f, 0.f, 0.f}, psvB = {0.f, 0.f, 0.f, 0.f};
#pragma unroll
    for (int g = 0; g < 4; ++g) {
      f32x4 b0 = *(const f32x4*)(bb + g * 8 + 4 * lh);
      f32x4 b1 = *(const f32x4*)(bb + 32 + g * 8 + 4 * lh);
#pragma unroll
      for (int r = 0; r < 4; ++r) {
        float pA0 = __builtin_amdgcn_exp2f(sA0[g * 4 + r] + b0[r]);
        float pA1 = __builtin_amdgcn_exp2f(sA1[g * 4 + r] + b1[r]);
        float pB0 = __builtin_amdgcn_exp2f(sB0[g * 4 + r] + b0[r]);
        float pB1 = __builtin_amdgcn_exp2f(sB1[g * 4 + r] + b1[r]);
        sA0[g * 4 + r] = pA0; sA1[g * 4 + r] = pA1;
        sB0[g * 4 + r] = pB0; sB1[g * 4 + r] = pB1;
        psvA[r] += pA0 + pA1;
        psvB[r] += pB0 + pB1;
      }
    }
    float psA = (psvA[0] + psvA[1]) + (psvA[2] + psvA[3]);
    float psB = (psvB[0] + psvB[1]) + (psvB[2] + psvB[3]);
    psA += __shfl_xor(psA, 32);
    psB += __shfl_xor(psB, 32);
    lsumA += psA;
    lsumB += psB;

    // ---- P·V, group A then group B (vf shared) ----
#pragma unroll
    for (int mc = 0; mc < 4; ++mc) {
      unsigned int c01, c23, c45, c67;
      {
        const int Rb = (mc & 1) * 8;
        if (mc < 2) {
          c01 = pkbf(sA0[Rb + 0], sA0[Rb + 1]); c23 = pkbf(sA0[Rb + 2], sA0[Rb + 3]);
          c45 = pkbf(sA0[Rb + 4], sA0[Rb + 5]); c67 = pkbf(sA0[Rb + 6], sA0[Rb + 7]);
        } else {
          c01 = pkbf(sA1[Rb + 0], sA1[Rb + 1]); c23 = pkbf(sA1[Rb + 2], sA1[Rb + 3]);
          c45 = pkbf(sA1[Rb + 4], sA1[Rb + 5]); c67 = pkbf(sA1[Rb + 6], sA1[Rb + 7]);
        }
      }
      unsigned int t01 = (unsigned int)__shfl_xor((int)c01, 32);
      unsigned int t23 = (unsigned int)__shfl_xor((int)c23, 32);
      unsigned int t45 = (unsigned int)__shfl_xor((int)c45, 32);
      unsigned int t67 = (unsigned int)__shfl_xor((int)c67, 32);
      FragU pa;
      pa.u[0] = lh ? t45 : c01;
      pa.u[1] = lh ? t67 : c23;
      pa.u[2] = lh ? c45 : t01;
      pa.u[3] = lh ? c67 : t23;
      __builtin_amdgcn_s_setprio(1);
      oA0 = __builtin_amdgcn_mfma_f32_32x32x16_bf16(pa.f, vf[mc][0], oA0, 0, 0, 0);
      oA1 = __builtin_amdgcn_mfma_f32_32x32x16_bf16(pa.f, vf[mc][1], oA1, 0, 0, 0);
      __builtin_amdgcn_s_setprio(0);
    }
#pragma unroll
    for (int mc = 0; mc < 4; ++mc) {
      unsigned int c01, c23, c45, c67;
      {
        const int Rb = (mc & 1) * 8;
        if (mc < 2) {
          c01 = pkbf(sB0[Rb + 0], sB0[Rb + 1]); c23 = pkbf(sB0[Rb + 2], sB0[Rb + 3]);
          c45 = pkbf(sB0[Rb + 4], sB0[Rb + 5]); c67 = pkbf(sB0[Rb + 6], sB0[Rb + 7]);
        } else {
          c01 = pkbf(sB1[Rb + 0], sB1[Rb + 1]); c23 = pkbf(sB1[Rb + 2], sB1[Rb + 3]);
          c45 = pkbf(sB1[Rb + 4], sB1[Rb + 5]); c67 = pkbf(sB1[Rb + 6], sB1[Rb + 7]);
        }
      }
      unsigned int t01 = (unsigned int)__shfl_xor((int)c01, 32);
      unsigned int t23 = (unsigned int)__shfl_xor((int)c23, 32);
      unsigned int t45 = (unsigned int)__shfl_xor((int)c45, 32);
      unsigned int t67 = (unsigned int)__shfl_xor((int)c67, 32);
      FragU pa;
      pa.u[0] = lh ? t45 : c01;
      pa.u[1] = lh ? t67 : c23;
      pa.u[2] = lh ? c45 : t01;
      pa.u[3] = lh ? c67 : t23;
      __builtin_amdgcn_s_setprio(1);
      oB0 = __builtin_amdgcn_mfma_f32_32x32x16_bf16(pa.f, vf[mc][0], oB0, 0, 0, 0);
      oB1 = __builtin_amdgcn_mfma_f32_32x32x16_bf16(pa.f, vf[mc][1], oB1, 0, 0, 0);
      __builtin_amdgcn_s_setprio(0);
    }
  }

  // ---- 8-way l merge per group (linear: no max tracking) ----
  if (lane < 32) { lArrA[wid * 32 + lane] = lsumA; lArrB[wid * 32 + lane] = lsumB; }
  __syncthreads();
  {
    float ltA = 0.f, ltB = 0.f;
#pragma unroll
    for (int w = 0; w < 8; ++w) { ltA += lArrA[w * 32 + lq]; ltB += lArrB[w * 32 + lq]; }
    if (wid == 0 && lane < 32) { IlvA[lane] = 1.f / ltA; IlvB[lane] = 1.f / ltB; }
  }
  __syncthreads();
#pragma unroll
  for (int g = 0; g < 4; ++g) {
    f32x4 IvA = *(const f32x4*)(IlvA + g * 8 + 4 * lh);
    f32x4 IvB = *(const f32x4*)(IlvB + g * 8 + 4 * lh);
#pragma unroll
    for (int rr = 0; rr < 4; ++rr) {
      oA0[g * 4 + rr] *= IvA[rr];
      oA1[g * 4 + rr] *= IvA[rr];
      oB0[g * 4 + rr] *= IvB[rr];
      oB1[g * 4 + rr] *= IvB[rr];
    }
  }
  // ---- O merge: group A through 4 LDS bufs, then group B (bufs reused) ----
  float* bufs = (float*)smem;                 // [4][32][64]
  float* dst = bufs + (wid & 3) * 2048;
  // group A
  if (wid < 4) {
#pragma unroll
    for (int r = 0; r < 16; ++r) {
      const int row = (r & 3) + 8 * (r >> 2) + 4 * lh;
      dst[row * 64 + lq]      = oA0[r];
      dst[row * 64 + 32 + lq] = oA1[r];
    }
  }
  __syncthreads();
  if (wid >= 4) {
#pragma unroll
    for (int r = 0; r < 16; ++r) {
      const int row = (r & 3) + 8 * (r >> 2) + 4 * lh;
      dst[row * 64 + lq]      += oA0[r];
      dst[row * 64 + 32 + lq] += oA1[r];
    }
  }
  __syncthreads();
  {
    float* op = outg + ((size_t)batch * N_ + qbase) * 64;
    const int i = tid * 4;   // 2048 floats over 512 thr
    f32x4 a0 = *(const f32x4*)(bufs + i);
    f32x4 a1 = *(const f32x4*)(bufs + 2048 + i);
    f32x4 a2 = *(const f32x4*)(bufs + 4096 + i);
    f32x4 a3 = *(const f32x4*)(bufs + 6144 + i);
#pragma unroll
    for (int r = 0; r < 4; ++r) a0[r] = (a0[r] + a1[r]) + (a2[r] + a3[r]);
    *(f32x4*)(op + i) = a0;
  }
  __syncthreads();
  // group B
  if (wid < 4) {
#pragma unroll
    for (int r = 0; r < 16; ++r) {
      const int row = (r & 3) + 8 * (r >> 2) + 4 * lh;
      dst[row * 64 + lq]      = oB0[r];
      dst[row * 64 + 32 + lq] = oB1[r];
    }
  }
  __syncthreads();
  if (wid >= 4) {
#pragma unroll
    for (int r = 0; r < 16; ++r) {
      const int row = (r & 3) + 8 * (r >> 2) + 4 * lh;
      dst[row * 64 + lq]      += oB0[r];
      dst[row * 64 + 32 + lq] += oB1[r];
    }
  }
  __syncthreads();
  {
    float* op = outg + ((size_t)batch * N_ + qbase + 32) * 64;
    const int i = tid * 4;
    f32x4 a0 = *(const f32x4*)(bufs + i);
    f32x4 a1 = *(const f32x4*)(bufs + 2048 + i);
    f32x4 a2 = *(const f32x4*)(bufs + 4096 + i);
    f32x4 a3 = *(const f32x4*)(bufs + 6144 + i);
#pragma unroll
    for (int r = 0; r < 4; ++r) a0[r] = (a0[r] + a1[r]) + (a2[r] + a3[r]);
    *(f32x4*)(op + i) = a0;
  }
}

// ---------------- fallback (R1, verified): used if ws too small ----------------
__device__ __forceinline__ unsigned int swz(unsigned int byte) {
  return byte ^ (((byte >> 7) & 7) << 4);
}

__global__ __launch_bounds__(256, 2) void attn_fused(
    const float* __restrict__ qg, const float* __restrict__ kg,
    const float* __restrict__ vg, const int* __restrict__ mqg,
    const int* __restrict__ mkg, float* __restrict__ outg)
{
  __shared__ alignas(16) char smem[35072];
  const int tid  = threadIdx.x;
  const int lane = tid & 63;
  const int lq   = lane & 31;
  const int lh   = lane >> 5;
  const int wid  = tid >> 6;
  const int khalf = wid >> 1;
  const int qrw  = (wid & 1) * 32;
  const int batch = blockIdx.x & 7;
  const int qbase = (blockIdx.x >> 3) * 64;

  char* Kl = smem + khalf * 8192;
  char* Vl = smem + 16384 + khalf * 8192;
  float* kbf    = (float*)(smem + 32768);
  float* alphav = (float*)(smem + 33280);
  float* mM     = (float*)(smem + 33792);
  float* mL     = (float*)(smem + 34048);
  float* bC0    = (float*)(smem + 34304);
  float* bC1    = (float*)(smem + 34560);

  const int grow = qbase + qrw + lq;
  const float qs = mqg[batch * N_ + grow] ? 0.1803368801111204f : 0.0f;
  bfrag qf[4];
  {
    const float* Qp = qg + ((size_t)batch * N_ + grow) * D_ + lh * 8;
#pragma unroll
    for (int c = 0; c < 4; ++c) {
      float4 a = *(const float4*)(Qp + c * 16);
      float4 b = *(const float4*)(Qp + c * 16 + 4);
      FragU f;
      f.u[0] = pkbf(a.x * qs, a.y * qs);
      f.u[1] = pkbf(a.z * qs, a.w * qs);
      f.u[2] = pkbf(b.x * qs, b.y * qs);
      f.u[3] = pkbf(b.z * qs, b.w * qs);
      qf[c] = f.f;
    }
  }

  const int sid   = tid & 127;
  const int shalf = tid >> 7;

  f32x16 o0, o1;
#pragma unroll
  for (int i = 0; i < 16; ++i) { o0[i] = 0.f; o1[i] = 0.f; }
  float m2 = -1e30f, lsum = 0.f;

  for (int t = 0; t < 32; ++t) {
    __syncthreads();
    {
      const int kb0 = shalf * 2048 + t * 64;
      const float4* K4 = (const float4*)(kg + ((size_t)batch * M_ + kb0) * D_);
      const float4* V4 = (const float4*)(vg + ((size_t)batch * M_ + kb0) * D_);
      char* Ks = smem + shalf * 8192;
      char* Vs = smem + 16384 + shalf * 8192;
#pragma unroll
      for (int j = 0; j < 8; ++j) {
        int idx = sid + j * 128;
        float4 a = K4[idx];
        int row = idx >> 4, col = (idx & 15) << 2;
        *(uint2*)(Ks + swz((unsigned)(row * 128 + col * 2))) =
            make_uint2(pkbf(a.x, a.y), pkbf(a.z, a.w));
        float4 b = V4[idx];
        int vk = idx >> 4, vc = (idx & 15) << 2;
        *(unsigned short*)(Vs + swz((unsigned)((vc + 0) * 128 + vk * 2))) = bf1(b.x);
        *(unsigned short*)(Vs + swz((unsigned)((vc + 1) * 128 + vk * 2))) = bf1(b.y);
        *(unsigned short*)(Vs + swz((unsigned)((vc + 2) * 128 + vk * 2))) = bf1(b.z);
        *(unsigned short*)(Vs + swz((unsigned)((vc + 3) * 128 + vk * 2))) = bf1(b.w);
      }
      if (sid < 64)
        kbf[shalf * 64 + sid] = mkg[batch * M_ + kb0 + sid] ? 0.f : -1e30f;
    }
    __syncthreads();

    f32x16 s0, s1;
#pragma unroll
    for (int i = 0; i < 16; ++i) { s0[i] = 0.f; s1[i] = 0.f; }
#pragma unroll
    for (int c = 0; c < 4; ++c) {
      bfrag kf0 = *(const bfrag*)(Kl + swz((unsigned)(lq * 128 + (c * 16 + lh * 8) * 2)));
      bfrag kf1 = *(const bfrag*)(Kl + swz((unsigned)((32 + lq) * 128 + (c * 16 + lh * 8) * 2)));
      s0 = __builtin_amdgcn_mfma_f32_32x32x16_bf16(kf0, qf[c], s0, 0, 0, 0);
      s1 = __builtin_amdgcn_mfma_f32_32x32x16_bf16(kf1, qf[c], s1, 0, 0, 0);
    }

    const float* kbh = kbf + khalf * 64;
    float mx = -1e30f;
#pragma unroll
    for (int g = 0; g < 4; ++g) {
      f32x4 b0 = *(const f32x4*)(kbh + g * 8 + 4 * lh);
      f32x4 b1 = *(const f32x4*)(kbh + 32 + g * 8 + 4 * lh);
#pragma unroll
      for (int r = 0; r < 4; ++r) {
        s0[g * 4 + r] += b0[r];
        s1[g * 4 + r] += b1[r];
        mx = fmaxf(mx, fmaxf(s0[g * 4 + r], s1[g * 4 + r]));
      }
    }
    mx = fmaxf(mx, __shfl_xor(mx, 32));

    if (__any(mx > m2 + 8.f)) {
      float mn = fmaxf(m2, mx);
      float al = __builtin_amdgcn_exp2f(m2 - mn);
      if (lane < 32) alphav[wid * 32 + lane] = al;
      asm volatile("s_waitcnt lgkmcnt(0)" ::: "memory");
#pragma unroll
      for (int g = 0; g < 4; ++g) {
        f32x4 av = *(const f32x4*)(alphav + wid * 32 + g * 8 + 4 * lh);
#pragma unroll
        for (int r = 0; r < 4; ++r) { o0[g * 4 + r] *= av[r]; o1[g * 4 + r] *= av[r]; }
      }
      lsum *= al;
      m2 = mn;
    }

    float ps = 0.f;
#pragma unroll
    for (int i = 0; i < 16; ++i) {
      float p0 = __builtin_amdgcn_exp2f(s0[i] - m2);
      float p1 = __builtin_amdgcn_exp2f(s1[i] - m2);
      s0[i] = p0; s1[i] = p1;
      ps += p0 + p1;
    }
    ps += __shfl_xor(ps, 32);
    lsum += ps;

#pragma unroll
    for (int mc = 0; mc < 4; ++mc) {
      unsigned int c01, c23, c45, c67;
      {
        const int Rb = (mc & 1) * 8;
        if (mc < 2) {
          c01 = pkbf(s0[Rb + 0], s0[Rb + 1]); c23 = pkbf(s0[Rb + 2], s0[Rb + 3]);
          c45 = pkbf(s0[Rb + 4], s0[Rb + 5]); c67 = pkbf(s0[Rb + 6], s0[Rb + 7]);
        } else {
          c01 = pkbf(s1[Rb + 0], s1[Rb + 1]); c23 = pkbf(s1[Rb + 2], s1[Rb + 3]);
          c45 = pkbf(s1[Rb + 4], s1[Rb + 5]); c67 = pkbf(s1[Rb + 6], s1[Rb + 7]);
        }
      }
      unsigned int t01 = (unsigned int)__shfl_xor((int)c01, 32);
      unsigned int t23 = (unsigned int)__shfl_xor((int)c23, 32);
      unsigned int t45 = (unsigned int)__shfl_xor((int)c45, 32);
      unsigned int t67 = (unsigned int)__shfl_xor((int)c67, 32);
      FragU pa;
      pa.u[0] = lh ? t45 : c01;
      pa.u[1] = lh ? t67 : c23;
      pa.u[2] = lh ? c45 : t01;
      pa.u[3] = lh ? c67 : t23;
      bfrag vf0 = *(const bfrag*)(Vl + swz((unsigned)(lq * 128 + (mc * 16 + lh * 8) * 2)));
      bfrag vf1 = *(const bfrag*)(Vl + swz((unsigned)((32 + lq) * 128 + (mc * 16 + lh * 8) * 2)));
      o0 = __builtin_amdgcn_mfma_f32_32x32x16_bf16(pa.f, vf0, o0, 0, 0, 0);
      o1 = __builtin_amdgcn_mfma_f32_32x32x16_bf16(pa.f, vf1, o1, 0, 0, 0);
    }
  }

  __syncthreads();
  float* Omg = (float*)smem;
  if (khalf == 1) {
    const int w = wid & 1;
    if (lane < 32) { mM[w * 32 + lane] = m2; mL[w * 32 + lane] = lsum; }
#pragma unroll
    for (int r = 0; r < 16; ++r) {
      const int row = (r & 3) + 8 * (r >> 2) + 4 * lh;
      Omg[w * 2048 + row * 64 + lq]      = o0[r];
      Omg[w * 2048 + row * 64 + 32 + lq] = o1[r];
    }
  }
  __syncthreads();
  if (khalf == 0) {
    const int w = wid & 1;
    float m1 = mM[w * 32 + lq], l1 = mL[w * 32 + lq];
    float msf = fmaxf(m2, m1);
    float c0 = __builtin_amdgcn_exp2f(m2 - msf);
    float c1 = __builtin_amdgcn_exp2f(m1 - msf);
    float il = 1.f / (lsum * c0 + l1 * c1);
    if (lane < 32) { bC0[w * 32 + lane] = c0 * il; bC1[w * 32 + lane] = c1 * il; }
    asm volatile("s_waitcnt lgkmcnt(0)" ::: "memory");
    float* outp = outg + ((size_t)batch * N_ + qbase + qrw) * 64;
#pragma unroll
    for (int g = 0; g < 4; ++g) {
      f32x4 a0 = *(const f32x4*)(bC0 + w * 32 + g * 8 + 4 * lh);
      f32x4 a1 = *(const f32x4*)(bC1 + w * 32 + g * 8 + 4 * lh);
#pragma unroll
      for (int rr = 0; rr < 4; ++rr) {
        const int r = g * 4 + rr;
        const int row = rr + 8 * g + 4 * lh;
        float r0 = o0[r] * a0[rr] + Omg[w * 2048 + row * 64 + lq]      * a1[rr];
        float r1 = o1[r] * a0[rr] + Omg[w * 2048 + row * 64 + 32 + lq] * a1[rr];
        outp[(size_t)row * 64 + lq]      = r0;
        outp[(size_t)row * 64 + 32 + lq] = r1;
      }
    }
  }
}

extern "C" void kernel_launch(void* const* d_in, const int* in_sizes, int n_in,
                              void* d_out, int out_size, void* d_ws, size_t ws_size,
                              hipStream_t stream) {
  const float* q  = (const float*)d_in[0];
  const float* k  = (const float*)d_in[1];
  const float* v  = (const float*)d_in[2];
  const int*   mq = (const int*)d_in[3];
  const int*   mk = (const int*)d_in[4];
  float* out = (float*)d_out;

  const size_t kp_off = 0;
  const size_t vp_off = (size_t)B_ * 64 * 8192;            // 4 MiB
  const size_t need   = vp_off * 2;                        // 8 MiB

  if (ws_size >= need) {
    char* kpack = (char*)d_ws + kp_off;
    char* vpack = (char*)d_ws + vp_off;
    attn_prepass<<<dim3(2048), dim3(256), 0, stream>>>(k, v, kpack, vpack);
    attn_main<<<dim3(512), dim3(512), 0, stream>>>(q, mq, mk, kpack, vpack, out);
  } else {
    attn_fused<<<dim3(512), dim3(256), 0, stream>>>(q, k, v, mq, mk, out);
  }
}

// Round 11
// 64.826 us; speedup vs baseline: 5.3418x; 5.3418x over previous
//
#include <hip/hip_runtime.h>

// Masked attention, b=8 n=m=4096 d=dv=64, f32 in/out.
// R11: R10 structure with launch_bounds(512,2) — R10's (512,4) clamped VGPR to
// 64 and spilled 1GB to scratch. Cap 256 lets the R9-verified 116-VGPR body
// allocate naturally -> 4 waves/SIMD from 512 blocks x 8 waves. QBLK=64/wave
// (halved VMEM, R9-verified) + 8-way key split per block.

#define B_ 8
#define N_ 4096
#define M_ 4096
#define D_ 64

typedef __attribute__((ext_vector_type(8))) __bf16 bfrag;
typedef __attribute__((ext_vector_type(16))) float f32x16;
typedef __attribute__((ext_vector_type(4))) float f32x4;

union FragU { bfrag f; unsigned int u[4]; };

__device__ __forceinline__ unsigned int pkbf(float lo, float hi) {
  unsigned short a = __builtin_bit_cast(unsigned short, (__bf16)lo);
  unsigned short b = __builtin_bit_cast(unsigned short, (__bf16)hi);
  return ((unsigned int)b << 16) | (unsigned int)a;
}
__device__ __forceinline__ unsigned short bf1(float x) {
  return __builtin_bit_cast(unsigned short, (__bf16)x);
}

// ---------------- prepass: pack fragment-order bf16 images ----------------
__global__ void attn_prepass(const float* __restrict__ kg, const float* __restrict__ vg,
                             char* __restrict__ kpack, char* __restrict__ vpack)
{
  const int bid = blockIdx.x, tid = threadIdx.x;
  if (bid < 1024) {
    const unsigned c0 = bid * 256 + tid;     // 0..262143
    const int lane = c0 & 63;
    const unsigned u = c0 >> 6;
    const int f = u & 1, c = (u >> 1) & 3, tile = (u >> 3) & 63, batch = u >> 9;
    const int lq = lane & 31, lh = lane >> 5;
    const int row = tile * 64 + f * 32 + lq;
    const float* src = kg + (((size_t)batch * M_ + row) * D_ + c * 16 + lh * 8);
    float4 a = ((const float4*)src)[0], b = ((const float4*)src)[1];
    uint4 o;
    o.x = pkbf(a.x, a.y); o.y = pkbf(a.z, a.w);
    o.z = pkbf(b.x, b.y); o.w = pkbf(b.z, b.w);
    *(uint4*)(kpack + (size_t)c0 * 16) = o;
  } else {
    const unsigned c0 = (bid - 1024) * 256 + tid;
    const int lane = c0 & 63;
    const unsigned u = c0 >> 6;
    const int f = u & 1, mc = (u >> 1) & 3, tile = (u >> 3) & 63, batch = u >> 9;
    const int lq = lane & 31, lh = lane >> 5;
    const int key0 = tile * 64 + mc * 16 + lh * 8;
    const int dv = f * 32 + lq;
    const float* base = vg + (((size_t)batch * M_ + key0) * D_ + dv);
    unsigned short h[8];
#pragma unroll
    for (int j = 0; j < 8; ++j) h[j] = bf1(base[(size_t)j * D_]);
    uint4 o;
    o.x = (unsigned)h[0] | ((unsigned)h[1] << 16);
    o.y = (unsigned)h[2] | ((unsigned)h[3] << 16);
    o.z = (unsigned)h[4] | ((unsigned)h[5] << 16);
    o.w = (unsigned)h[6] | ((unsigned)h[7] << 16);
    *(uint4*)(vpack + (size_t)c0 * 16) = o;
  }
}

// ---------------- main kernel: 512 thr, 8-way key split, QBLK=64/wave --------
// LDS: loop: bias[4096] f32 in [0,16384)
//      epilogue: bufs[4][32][64] f32 = 32768 (reused for group A then B)
//      32768 lArrA[8][32]; 33792 lArrB[8][32]; 34816 IlvA[32]; 34944 IlvB[32]
__global__ __launch_bounds__(512, 2) void attn_main(
    const float* __restrict__ qg, const int* __restrict__ mqg,
    const int* __restrict__ mkg, const char* __restrict__ kpack,
    const char* __restrict__ vpack, float* __restrict__ outg)
{
  __shared__ alignas(16) char smem[35072];
  const int tid  = threadIdx.x;
  const int lane = tid & 63;
  const int lq   = lane & 31;
  const int lh   = lane >> 5;
  const int wid  = tid >> 6;            // key eighth, 0..7
  const int batch = blockIdx.x & 7;     // batch == XCD for L2 locality
  const int qbase = (blockIdx.x >> 3) * 64;

  float* lArrA = (float*)(smem + 32768);
  float* lArrB = (float*)(smem + 33792);
  float* IlvA  = (float*)(smem + 34816);
  float* IlvB  = (float*)(smem + 34944);

  // ---- stage key bias into LDS (cooperative, broadcast-read later) ----
  {
    const int4* mk4 = (const int4*)(mkg + batch * M_);
    float* bl = (float*)smem;
#pragma unroll
    for (int j = 0; j < 2; ++j) {
      const int i4 = tid + j * 512;
      int4 m4 = mk4[i4];
      f32x4 bv;
      bv[0] = m4.x ? 0.f : -1e30f;
      bv[1] = m4.y ? 0.f : -1e30f;
      bv[2] = m4.z ? 0.f : -1e30f;
      bv[3] = m4.w ? 0.f : -1e30f;
      *(f32x4*)(bl + i4 * 4) = bv;
    }
  }

  // ---- Q frags for both 32-row groups (A: rows +lq, B: rows +32+lq) ----
  bfrag qfA[4], qfB[4];
  {
    const int growA = qbase + lq;
    const float qsA = mqg[batch * N_ + growA] ? 0.1803368801111204f : 0.0f;
    const float* QpA = qg + ((size_t)batch * N_ + growA) * D_ + lh * 8;
#pragma unroll
    for (int c = 0; c < 4; ++c) {
      float4 a = *(const float4*)(QpA + c * 16);
      float4 b = *(const float4*)(QpA + c * 16 + 4);
      FragU f;
      f.u[0] = pkbf(a.x * qsA, a.y * qsA);
      f.u[1] = pkbf(a.z * qsA, a.w * qsA);
      f.u[2] = pkbf(b.x * qsA, b.y * qsA);
      f.u[3] = pkbf(b.z * qsA, b.w * qsA);
      qfA[c] = f.f;
    }
    const int growB = qbase + 32 + lq;
    const float qsB = mqg[batch * N_ + growB] ? 0.1803368801111204f : 0.0f;
    const float* QpB = qg + ((size_t)batch * N_ + growB) * D_ + lh * 8;
#pragma unroll
    for (int c = 0; c < 4; ++c) {
      float4 a = *(const float4*)(QpB + c * 16);
      float4 b = *(const float4*)(QpB + c * 16 + 4);
      FragU f;
      f.u[0] = pkbf(a.x * qsB, a.y * qsB);
      f.u[1] = pkbf(a.z * qsB, a.w * qsB);
      f.u[2] = pkbf(b.x * qsB, b.y * qsB);
      f.u[3] = pkbf(b.z * qsB, b.w * qsB);
      qfB[c] = f.f;
    }
  }
  __syncthreads();  // bias staged

  f32x16 oA0, oA1, oB0, oB1;
#pragma unroll
  for (int i = 0; i < 16; ++i) { oA0[i] = 0.f; oA1[i] = 0.f; oB0[i] = 0.f; oB1[i] = 0.f; }
  float lsumA = 0.f, lsumB = 0.f;

  const float* blw = (const float*)smem + wid * 512;

  for (int t8 = 0; t8 < 8; ++t8) {
    const int tile = wid * 8 + t8;
    const size_t tb = (size_t)(batch * 64 + tile) * 8192 + (size_t)lane * 16;

    // ---- K + V frags (one load set feeds both q-groups) ----
    bfrag kf[4][2];
#pragma unroll
    for (int c = 0; c < 4; ++c) {
      kf[c][0] = *(const bfrag*)(kpack + tb + (c * 2 + 0) * 1024);
      kf[c][1] = *(const bfrag*)(kpack + tb + (c * 2 + 1) * 1024);
    }
    bfrag vf[4][2];
#pragma unroll
    for (int mc = 0; mc < 4; ++mc) {
      vf[mc][0] = *(const bfrag*)(vpack + tb + (mc * 2 + 0) * 1024);
      vf[mc][1] = *(const bfrag*)(vpack + tb + (mc * 2 + 1) * 1024);
    }

    // ---- swapped QK^T for both groups ----
    f32x16 sA0, sA1, sB0, sB1;
#pragma unroll
    for (int i = 0; i < 16; ++i) { sA0[i] = 0.f; sA1[i] = 0.f; sB0[i] = 0.f; sB1[i] = 0.f; }
    __builtin_amdgcn_s_setprio(1);
#pragma unroll
    for (int c = 0; c < 4; ++c) {
      sA0 = __builtin_amdgcn_mfma_f32_32x32x16_bf16(kf[c][0], qfA[c], sA0, 0, 0, 0);
      sA1 = __builtin_amdgcn_mfma_f32_32x32x16_bf16(kf[c][1], qfA[c], sA1, 0, 0, 0);
      sB0 = __builtin_amdgcn_mfma_f32_32x32x16_bf16(kf[c][0], qfB[c], sB0, 0, 0, 0);
      sB1 = __builtin_amdgcn_mfma_f32_32x32x16_bf16(kf[c][1], qfB[c], sB1, 0, 0, 0);
    }
    __builtin_amdgcn_s_setprio(0);

    // ---- softmax numerators, both groups (bias shared; no max: R7) ----
    const float* bb = blw + t8 * 64;
    f32x4 psvA = {0.f, 0.f, 0.f, 0.f}, psvB = {0.f, 0.f, 0.f, 0.f};
#pragma unroll
    for (int g = 0; g < 4; ++g) {
      f32x4 b0 = *(const f32x4*)(bb + g * 8 + 4 * lh);
      f32x4 b1 = *(const f32x4*)(bb + 32 + g * 8 + 4 * lh);
#pragma unroll
      for (int r = 0; r < 4; ++r) {
        float pA0 = __builtin_amdgcn_exp2f(sA0[g * 4 + r] + b0[r]);
        float pA1 = __builtin_amdgcn_exp2f(sA1[g * 4 + r] + b1[r]);
        float pB0 = __builtin_amdgcn_exp2f(sB0[g * 4 + r] + b0[r]);
        float pB1 = __builtin_amdgcn_exp2f(sB1[g * 4 + r] + b1[r]);
        sA0[g * 4 + r] = pA0; sA1[g * 4 + r] = pA1;
        sB0[g * 4 + r] = pB0; sB1[g * 4 + r] = pB1;
        psvA[r] += pA0 + pA1;
        psvB[r] += pB0 + pB1;
      }
    }
    float psA = (psvA[0] + psvA[1]) + (psvA[2] + psvA[3]);
    float psB = (psvB[0] + psvB[1]) + (psvB[2] + psvB[3]);
    psA += __shfl_xor(psA, 32);
    psB += __shfl_xor(psB, 32);
    lsumA += psA;
    lsumB += psB;

    // ---- P·V, group A then group B (vf shared) ----
#pragma unroll
    for (int mc = 0; mc < 4; ++mc) {
      unsigned int c01, c23, c45, c67;
      {
        const int Rb = (mc & 1) * 8;
        if (mc < 2) {
          c01 = pkbf(sA0[Rb + 0], sA0[Rb + 1]); c23 = pkbf(sA0[Rb + 2], sA0[Rb + 3]);
          c45 = pkbf(sA0[Rb + 4], sA0[Rb + 5]); c67 = pkbf(sA0[Rb + 6], sA0[Rb + 7]);
        } else {
          c01 = pkbf(sA1[Rb + 0], sA1[Rb + 1]); c23 = pkbf(sA1[Rb + 2], sA1[Rb + 3]);
          c45 = pkbf(sA1[Rb + 4], sA1[Rb + 5]); c67 = pkbf(sA1[Rb + 6], sA1[Rb + 7]);
        }
      }
      unsigned int t01 = (unsigned int)__shfl_xor((int)c01, 32);
      unsigned int t23 = (unsigned int)__shfl_xor((int)c23, 32);
      unsigned int t45 = (unsigned int)__shfl_xor((int)c45, 32);
      unsigned int t67 = (unsigned int)__shfl_xor((int)c67, 32);
      FragU pa;
      pa.u[0] = lh ? t45 : c01;
      pa.u[1] = lh ? t67 : c23;
      pa.u[2] = lh ? c45 : t01;
      pa.u[3] = lh ? c67 : t23;
      __builtin_amdgcn_s_setprio(1);
      oA0 = __builtin_amdgcn_mfma_f32_32x32x16_bf16(pa.f, vf[mc][0], oA0, 0, 0, 0);
      oA1 = __builtin_amdgcn_mfma_f32_32x32x16_bf16(pa.f, vf[mc][1], oA1, 0, 0, 0);
      __builtin_amdgcn_s_setprio(0);
    }
#pragma unroll
    for (int mc = 0; mc < 4; ++mc) {
      unsigned int c01, c23, c45, c67;
      {
        const int Rb = (mc & 1) * 8;
        if (mc < 2) {
          c01 = pkbf(sB0[Rb + 0], sB0[Rb + 1]); c23 = pkbf(sB0[Rb + 2], sB0[Rb + 3]);
          c45 = pkbf(sB0[Rb + 4], sB0[Rb + 5]); c67 = pkbf(sB0[Rb + 6], sB0[Rb + 7]);
        } else {
          c01 = pkbf(sB1[Rb + 0], sB1[Rb + 1]); c23 = pkbf(sB1[Rb + 2], sB1[Rb + 3]);
          c45 = pkbf(sB1[Rb + 4], sB1[Rb + 5]); c67 = pkbf(sB1[Rb + 6], sB1[Rb + 7]);
        }
      }
      unsigned int t01 = (unsigned int)__shfl_xor((int)c01, 32);
      unsigned int t23 = (unsigned int)__shfl_xor((int)c23, 32);
      unsigned int t45 = (unsigned int)__shfl_xor((int)c45, 32);
      unsigned int t67 = (unsigned int)__shfl_xor((int)c67, 32);
      FragU pa;
      pa.u[0] = lh ? t45 : c01;
      pa.u[1] = lh ? t67 : c23;
      pa.u[2] = lh ? c45 : t01;
      pa.u[3] = lh ? c67 : t23;
      __builtin_amdgcn_s_setprio(1);
      oB0 = __builtin_amdgcn_mfma_f32_32x32x16_bf16(pa.f, vf[mc][0], oB0, 0, 0, 0);
      oB1 = __builtin_amdgcn_mfma_f32_32x32x16_bf16(pa.f, vf[mc][1], oB1, 0, 0, 0);
      __builtin_amdgcn_s_setprio(0);
    }
  }

  // ---- 8-way l merge per group (linear: no max tracking) ----
  if (lane < 32) { lArrA[wid * 32 + lane] = lsumA; lArrB[wid * 32 + lane] = lsumB; }
  __syncthreads();
  {
    float ltA = 0.f, ltB = 0.f;
#pragma unroll
    for (int w = 0; w < 8; ++w) { ltA += lArrA[w * 32 + lq]; ltB += lArrB[w * 32 + lq]; }
    if (wid == 0 && lane < 32) { IlvA[lane] = 1.f / ltA; IlvB[lane] = 1.f / ltB; }
  }
  __syncthreads();
#pragma unroll
  for (int g = 0; g < 4; ++g) {
    f32x4 IvA = *(const f32x4*)(IlvA + g * 8 + 4 * lh);
    f32x4 IvB = *(const f32x4*)(IlvB + g * 8 + 4 * lh);
#pragma unroll
    for (int rr = 0; rr < 4; ++rr) {
      oA0[g * 4 + rr] *= IvA[rr];
      oA1[g * 4 + rr] *= IvA[rr];
      oB0[g * 4 + rr] *= IvB[rr];
      oB1[g * 4 + rr] *= IvB[rr];
    }
  }
  // ---- O merge: group A through 4 LDS bufs, then group B (bufs reused) ----
  float* bufs = (float*)smem;                 // [4][32][64]
  float* dst = bufs + (wid & 3) * 2048;
  // group A
  if (wid < 4) {
#pragma unroll
    for (int r = 0; r < 16; ++r) {
      const int row = (r & 3) + 8 * (r >> 2) + 4 * lh;
      dst[row * 64 + lq]      = oA0[r];
      dst[row * 64 + 32 + lq] = oA1[r];
    }
  }
  __syncthreads();
  if (wid >= 4) {
#pragma unroll
    for (int r = 0; r < 16; ++r) {
      const int row = (r & 3) + 8 * (r >> 2) + 4 * lh;
      dst[row * 64 + lq]      += oA0[r];
      dst[row * 64 + 32 + lq] += oA1[r];
    }
  }
  __syncthreads();
  {
    float* op = outg + ((size_t)batch * N_ + qbase) * 64;
    const int i = tid * 4;   // 2048 floats over 512 thr
    f32x4 a0 = *(const f32x4*)(bufs + i);
    f32x4 a1 = *(const f32x4*)(bufs + 2048 + i);
    f32x4 a2 = *(const f32x4*)(bufs + 4096 + i);
    f32x4 a3 = *(const f32x4*)(bufs + 6144 + i);
#pragma unroll
    for (int r = 0; r < 4; ++r) a0[r] = (a0[r] + a1[r]) + (a2[r] + a3[r]);
    *(f32x4*)(op + i) = a0;
  }
  __syncthreads();
  // group B
  if (wid < 4) {
#pragma unroll
    for (int r = 0; r < 16; ++r) {
      const int row = (r & 3) + 8 * (r >> 2) + 4 * lh;
      dst[row * 64 + lq]      = oB0[r];
      dst[row * 64 + 32 + lq] = oB1[r];
    }
  }
  __syncthreads();
  if (wid >= 4) {
#pragma unroll
    for (int r = 0; r < 16; ++r) {
      const int row = (r & 3) + 8 * (r >> 2) + 4 * lh;
      dst[row * 64 + lq]      += oB0[r];
      dst[row * 64 + 32 + lq] += oB1[r];
    }
  }
  __syncthreads();
  {
    float* op = outg + ((size_t)batch * N_ + qbase + 32) * 64;
    const int i = tid * 4;
    f32x4 a0 = *(const f32x4*)(bufs + i);
    f32x4 a1 = *(const f32x4*)(bufs + 2048 + i);
    f32x4 a2 = *(const f32x4*)(bufs + 4096 + i);
    f32x4 a3 = *(const f32x4*)(bufs + 6144 + i);
#pragma unroll
    for (int r = 0; r < 4; ++r) a0[r] = (a0[r] + a1[r]) + (a2[r] + a3[r]);
    *(f32x4*)(op + i) = a0;
  }
}

// ---------------- fallback (R1, verified): used if ws too small ----------------
__device__ __forceinline__ unsigned int swz(unsigned int byte) {
  return byte ^ (((byte >> 7) & 7) << 4);
}

__global__ __launch_bounds__(256, 2) void attn_fused(
    const float* __restrict__ qg, const float* __restrict__ kg,
    const float* __restrict__ vg, const int* __restrict__ mqg,
    const int* __restrict__ mkg, float* __restrict__ outg)
{
  __shared__ alignas(16) char smem[35072];
  const int tid  = threadIdx.x;
  const int lane = tid & 63;
  const int lq   = lane & 31;
  const int lh   = lane >> 5;
  const int wid  = tid >> 6;
  const int khalf = wid >> 1;
  const int qrw  = (wid & 1) * 32;
  const int batch = blockIdx.x & 7;
  const int qbase = (blockIdx.x >> 3) * 64;

  char* Kl = smem + khalf * 8192;
  char* Vl = smem + 16384 + khalf * 8192;
  float* kbf    = (float*)(smem + 32768);
  float* alphav = (float*)(smem + 33280);
  float* mM     = (float*)(smem + 33792);
  float* mL     = (float*)(smem + 34048);
  float* bC0    = (float*)(smem + 34304);
  float* bC1    = (float*)(smem + 34560);

  const int grow = qbase + qrw + lq;
  const float qs = mqg[batch * N_ + grow] ? 0.1803368801111204f : 0.0f;
  bfrag qf[4];
  {
    const float* Qp = qg + ((size_t)batch * N_ + grow) * D_ + lh * 8;
#pragma unroll
    for (int c = 0; c < 4; ++c) {
      float4 a = *(const float4*)(Qp + c * 16);
      float4 b = *(const float4*)(Qp + c * 16 + 4);
      FragU f;
      f.u[0] = pkbf(a.x * qs, a.y * qs);
      f.u[1] = pkbf(a.z * qs, a.w * qs);
      f.u[2] = pkbf(b.x * qs, b.y * qs);
      f.u[3] = pkbf(b.z * qs, b.w * qs);
      qf[c] = f.f;
    }
  }

  const int sid   = tid & 127;
  const int shalf = tid >> 7;

  f32x16 o0, o1;
#pragma unroll
  for (int i = 0; i < 16; ++i) { o0[i] = 0.f; o1[i] = 0.f; }
  float m2 = -1e30f, lsum = 0.f;

  for (int t = 0; t < 32; ++t) {
    __syncthreads();
    {
      const int kb0 = shalf * 2048 + t * 64;
      const float4* K4 = (const float4*)(kg + ((size_t)batch * M_ + kb0) * D_);
      const float4* V4 = (const float4*)(vg + ((size_t)batch * M_ + kb0) * D_);
      char* Ks = smem + shalf * 8192;
      char* Vs = smem + 16384 + shalf * 8192;
#pragma unroll
      for (int j = 0; j < 8; ++j) {
        int idx = sid + j * 128;
        float4 a = K4[idx];
        int row = idx >> 4, col = (idx & 15) << 2;
        *(uint2*)(Ks + swz((unsigned)(row * 128 + col * 2))) =
            make_uint2(pkbf(a.x, a.y), pkbf(a.z, a.w));
        float4 b = V4[idx];
        int vk = idx >> 4, vc = (idx & 15) << 2;
        *(unsigned short*)(Vs + swz((unsigned)((vc + 0) * 128 + vk * 2))) = bf1(b.x);
        *(unsigned short*)(Vs + swz((unsigned)((vc + 1) * 128 + vk * 2))) = bf1(b.y);
        *(unsigned short*)(Vs + swz((unsigned)((vc + 2) * 128 + vk * 2))) = bf1(b.z);
        *(unsigned short*)(Vs + swz((unsigned)((vc + 3) * 128 + vk * 2))) = bf1(b.w);
      }
      if (sid < 64)
        kbf[shalf * 64 + sid] = mkg[batch * M_ + kb0 + sid] ? 0.f : -1e30f;
    }
    __syncthreads();

    f32x16 s0, s1;
#pragma unroll
    for (int i = 0; i < 16; ++i) { s0[i] = 0.f; s1[i] = 0.f; }
#pragma unroll
    for (int c = 0; c < 4; ++c) {
      bfrag kf0 = *(const bfrag*)(Kl + swz((unsigned)(lq * 128 + (c * 16 + lh * 8) * 2)));
      bfrag kf1 = *(const bfrag*)(Kl + swz((unsigned)((32 + lq) * 128 + (c * 16 + lh * 8) * 2)));
      s0 = __builtin_amdgcn_mfma_f32_32x32x16_bf16(kf0, qf[c], s0, 0, 0, 0);
      s1 = __builtin_amdgcn_mfma_f32_32x32x16_bf16(kf1, qf[c], s1, 0, 0, 0);
    }

    const float* kbh = kbf + khalf * 64;
    float mx = -1e30f;
#pragma unroll
    for (int g = 0; g < 4; ++g) {
      f32x4 b0 = *(const f32x4*)(kbh + g * 8 + 4 * lh);
      f32x4 b1 = *(const f32x4*)(kbh + 32 + g * 8 + 4 * lh);
#pragma unroll
      for (int r = 0; r < 4; ++r) {
        s0[g * 4 + r] += b0[r];
        s1[g * 4 + r] += b1[r];
        mx = fmaxf(mx, fmaxf(s0[g * 4 + r], s1[g * 4 + r]));
      }
    }
    mx = fmaxf(mx, __shfl_xor(mx, 32));

    if (__any(mx > m2 + 8.f)) {
      float mn = fmaxf(m2, mx);
      float al = __builtin_amdgcn_exp2f(m2 - mn);
      if (lane < 32) alphav[wid * 32 + lane] = al;
      asm volatile("s_waitcnt lgkmcnt(0)" ::: "memory");
#pragma unroll
      for (int g = 0; g < 4; ++g) {
        f32x4 av = *(const f32x4*)(alphav + wid * 32 + g * 8 + 4 * lh);
#pragma unroll
        for (int r = 0; r < 4; ++r) { o0[g * 4 + r] *= av[r]; o1[g * 4 + r] *= av[r]; }
      }
      lsum *= al;
      m2 = mn;
    }

    float ps = 0.f;
#pragma unroll
    for (int i = 0; i < 16; ++i) {
      float p0 = __builtin_amdgcn_exp2f(s0[i] - m2);
      float p1 = __builtin_amdgcn_exp2f(s1[i] - m2);
      s0[i] = p0; s1[i] = p1;
      ps += p0 + p1;
    }
    ps += __shfl_xor(ps, 32);
    lsum += ps;

#pragma unroll
    for (int mc = 0; mc < 4; ++mc) {
      unsigned int c01, c23, c45, c67;
      {
        const int Rb = (mc & 1) * 8;
        if (mc < 2) {
          c01 = pkbf(s0[Rb + 0], s0[Rb + 1]); c23 = pkbf(s0[Rb + 2], s0[Rb + 3]);
          c45 = pkbf(s0[Rb + 4], s0[Rb + 5]); c67 = pkbf(s0[Rb + 6], s0[Rb + 7]);
        } else {
          c01 = pkbf(s1[Rb + 0], s1[Rb + 1]); c23 = pkbf(s1[Rb + 2], s1[Rb + 3]);
          c45 = pkbf(s1[Rb + 4], s1[Rb + 5]); c67 = pkbf(s1[Rb + 6], s1[Rb + 7]);
        }
      }
      unsigned int t01 = (unsigned int)__shfl_xor((int)c01, 32);
      unsigned int t23 = (unsigned int)__shfl_xor((int)c23, 32);
      unsigned int t45 = (unsigned int)__shfl_xor((int)c45, 32);
      unsigned int t67 = (unsigned int)__shfl_xor((int)c67, 32);
      FragU pa;
      pa.u[0] = lh ? t45 : c01;
      pa.u[1] = lh ? t67 : c23;
      pa.u[2] = lh ? c45 : t01;
      pa.u[3] = lh ? c67 : t23;
      bfrag vf0 = *(const bfrag*)(Vl + swz((unsigned)(lq * 128 + (mc * 16 + lh * 8) * 2)));
      bfrag vf1 = *(const bfrag*)(Vl + swz((unsigned)((32 + lq) * 128 + (mc * 16 + lh * 8) * 2)));
      o0 = __builtin_amdgcn_mfma_f32_32x32x16_bf16(pa.f, vf0, o0, 0, 0, 0);
      o1 = __builtin_amdgcn_mfma_f32_32x32x16_bf16(pa.f, vf1, o1, 0, 0, 0);
    }
  }

  __syncthreads();
  float* Omg = (float*)smem;
  if (khalf == 1) {
    const int w = wid & 1;
    if (lane < 32) { mM[w * 32 + lane] = m2; mL[w * 32 + lane] = lsum; }
#pragma unroll
    for (int r = 0; r < 16; ++r) {
      const int row = (r & 3) + 8 * (r >> 2) + 4 * lh;
      Omg[w * 2048 + row * 64 + lq]      = o0[r];
      Omg[w * 2048 + row * 64 + 32 + lq] = o1[r];
    }
  }
  __syncthreads();
  if (khalf == 0) {
    const int w = wid & 1;
    float m1 = mM[w * 32 + lq], l1 = mL[w * 32 + lq];
    float msf = fmaxf(m2, m1);
    float c0 = __builtin_amdgcn_exp2f(m2 - msf);
    float c1 = __builtin_amdgcn_exp2f(m1 - msf);
    float il = 1.f / (lsum * c0 + l1 * c1);
    if (lane < 32) { bC0[w * 32 + lane] = c0 * il; bC1[w * 32 + lane] = c1 * il; }
    asm volatile("s_waitcnt lgkmcnt(0)" ::: "memory");
    float* outp = outg + ((size_t)batch * N_ + qbase + qrw) * 64;
#pragma unroll
    for (int g = 0; g < 4; ++g) {
      f32x4 a0 = *(const f32x4*)(bC0 + w * 32 + g * 8 + 4 * lh);
      f32x4 a1 = *(const f32x4*)(bC1 + w * 32 + g * 8 + 4 * lh);
#pragma unroll
      for (int rr = 0; rr < 4; ++rr) {
        const int r = g * 4 + rr;
        const int row = rr + 8 * g + 4 * lh;
        float r0 = o0[r] * a0[rr] + Omg[w * 2048 + row * 64 + lq]      * a1[rr];
        float r1 = o1[r] * a0[rr] + Omg[w * 2048 + row * 64 + 32 + lq] * a1[rr];
        outp[(size_t)row * 64 + lq]      = r0;
        outp[(size_t)row * 64 + 32 + lq] = r1;
      }
    }
  }
}

extern "C" void kernel_launch(void* const* d_in, const int* in_sizes, int n_in,
                              void* d_out, int out_size, void* d_ws, size_t ws_size,
                              hipStream_t stream) {
  const float* q  = (const float*)d_in[0];
  const float* k  = (const float*)d_in[1];
  const float* v  = (const float*)d_in[2];
  const int*   mq = (const int*)d_in[3];
  const int*   mk = (const int*)d_in[4];
  float* out = (float*)d_out;

  const size_t kp_off = 0;
  const size_t vp_off = (size_t)B_ * 64 * 8192;            // 4 MiB
  const size_t need   = vp_off * 2;                        // 8 MiB

  if (ws_size >= need) {
    char* kpack = (char*)d_ws + kp_off;
    char* vpack = (char*)d_ws + vp_off;
    attn_prepass<<<dim3(2048), dim3(256), 0, stream>>>(k, v, kpack, vpack);
    attn_main<<<dim3(512), dim3(512), 0, stream>>>(q, mq, mk, kpack, vpack, out);
  } else {
    attn_fused<<<dim3(512), dim3(256), 0, stream>>>(q, k, v, mq, mk, out);
  }
}

// Round 13
// 55.641 us; speedup vs baseline: 6.2236x; 1.1651x over previous
//
#include <hip/hip_runtime.h>

// Masked attention, b=8 n=m=4096 d=dv=64, f32 in/out.
// R13: R9 geometry (256 thr / 4 waves / 16 tiles, QBLK=64) + key-permuted
// kpack: placing key swap_bits23(row) at MFMA A-row makes PV's A-frag a pure
// own-register repack — deletes ALL cross-lane shuffles/selects from the loop
// (R12's permlane semantics gamble failed; this is correct by construction).
// Key bias staged with the same involutive permutation; l-reduce deferred.

#define B_ 8
#define N_ 4096
#define M_ 4096
#define D_ 64

typedef __attribute__((ext_vector_type(8))) __bf16 bfrag;
typedef __attribute__((ext_vector_type(16))) float f32x16;
typedef __attribute__((ext_vector_type(4))) float f32x4;

union FragU { bfrag f; unsigned int u[4]; };

__device__ __forceinline__ unsigned int pkbf(float lo, float hi) {
  unsigned short a = __builtin_bit_cast(unsigned short, (__bf16)lo);
  unsigned short b = __builtin_bit_cast(unsigned short, (__bf16)hi);
  return ((unsigned int)b << 16) | (unsigned int)a;
}
__device__ __forceinline__ unsigned short bf1(float x) {
  return __builtin_bit_cast(unsigned short, (__bf16)x);
}

// ---------------- prepass: pack fragment-order bf16 images ----------------
// kpack: key PERMUTED (swap bits 2<->3 of the 32-row index) so QK^T's C/D rows
// land exactly where PV's A-operand wants them (zero cross-lane exchange).
// vpack unchanged.
__global__ void attn_prepass(const float* __restrict__ kg, const float* __restrict__ vg,
                             char* __restrict__ kpack, char* __restrict__ vpack)
{
  const int bid = blockIdx.x, tid = threadIdx.x;
  if (bid < 1024) {
    const unsigned c0 = bid * 256 + tid;     // 0..262143
    const int lane = c0 & 63;
    const unsigned u = c0 >> 6;
    const int f = u & 1, c = (u >> 1) & 3, tile = (u >> 3) & 63, batch = u >> 9;
    const int lq = lane & 31, lh = lane >> 5;
    const int lqp = (lq & 19) | ((lq & 4) << 1) | ((lq & 8) >> 1);  // swap bits 2,3
    const int row = tile * 64 + f * 32 + lqp;
    const float* src = kg + (((size_t)batch * M_ + row) * D_ + c * 16 + lh * 8);
    float4 a = ((const float4*)src)[0], b = ((const float4*)src)[1];
    uint4 o;
    o.x = pkbf(a.x, a.y); o.y = pkbf(a.z, a.w);
    o.z = pkbf(b.x, b.y); o.w = pkbf(b.z, b.w);
    *(uint4*)(kpack + (size_t)c0 * 16) = o;
  } else {
    const unsigned c0 = (bid - 1024) * 256 + tid;
    const int lane = c0 & 63;
    const unsigned u = c0 >> 6;
    const int f = u & 1, mc = (u >> 1) & 3, tile = (u >> 3) & 63, batch = u >> 9;
    const int lq = lane & 31, lh = lane >> 5;
    const int key0 = tile * 64 + mc * 16 + lh * 8;
    const int dv = f * 32 + lq;
    const float* base = vg + (((size_t)batch * M_ + key0) * D_ + dv);
    unsigned short h[8];
#pragma unroll
    for (int j = 0; j < 8; ++j) h[j] = bf1(base[(size_t)j * D_]);
    uint4 o;
    o.x = (unsigned)h[0] | ((unsigned)h[1] << 16);
    o.y = (unsigned)h[2] | ((unsigned)h[3] << 16);
    o.z = (unsigned)h[4] | ((unsigned)h[5] << 16);
    o.w = (unsigned)h[6] | ((unsigned)h[7] << 16);
    *(uint4*)(vpack + (size_t)c0 * 16) = o;
  }
}

// ---------------- main kernel: 256 thr, 4-way key split, QBLK=64/wave --------
// LDS: loop: bias[4096] f32 in [0,16384)  (PERMUTED to match kpack rows)
//      epilogue: bufs [2 groups][2][32][64] f32 = 32768 (reuses [0,32768))
//      32768 lArrA[4][32]; 33280 lArrB[4][32]; 33792 IlvA[32]; 33920 IlvB[32]
__global__ __launch_bounds__(256, 2) void attn_main(
    const float* __restrict__ qg, const int* __restrict__ mqg,
    const int* __restrict__ mkg, const char* __restrict__ kpack,
    const char* __restrict__ vpack, float* __restrict__ outg)
{
  __shared__ alignas(16) char smem[34048];
  const int tid  = threadIdx.x;
  const int lane = tid & 63;
  const int lq   = lane & 31;
  const int lh   = lane >> 5;
  const int wid  = tid >> 6;            // key quarter, 0..3
  const int batch = blockIdx.x & 7;     // batch == XCD for L2 locality
  const int qbase = (blockIdx.x >> 3) * 64;

  float* lArrA = (float*)(smem + 32768);
  float* lArrB = (float*)(smem + 33280);
  float* IlvA  = (float*)(smem + 33792);
  float* IlvB  = (float*)(smem + 33920);

  // ---- stage key bias into LDS, permuted: biasLDS[i] = bias[swap23(i)] ----
  {
    const int4* mk4 = (const int4*)(mkg + batch * M_);
    float* bl = (float*)smem;
#pragma unroll
    for (int j = 0; j < 4; ++j) {
      const int i4 = tid + j * 256;
      const int i4s = (i4 & ~3) | ((i4 & 1) << 1) | ((i4 >> 1) & 1);  // swap bits 0,1
      int4 m4 = mk4[i4s];
      f32x4 bv;
      bv[0] = m4.x ? 0.f : -1e30f;
      bv[1] = m4.y ? 0.f : -1e30f;
      bv[2] = m4.z ? 0.f : -1e30f;
      bv[3] = m4.w ? 0.f : -1e30f;
      *(f32x4*)(bl + i4 * 4) = bv;
    }
  }

  // ---- Q frags for both 32-row groups (A: rows +lq, B: rows +32+lq) ----
  bfrag qfA[4], qfB[4];
  {
    const int growA = qbase + lq;
    const float qsA = mqg[batch * N_ + growA] ? 0.1803368801111204f : 0.0f;
    const float* QpA = qg + ((size_t)batch * N_ + growA) * D_ + lh * 8;
#pragma unroll
    for (int c = 0; c < 4; ++c) {
      float4 a = *(const float4*)(QpA + c * 16);
      float4 b = *(const float4*)(QpA + c * 16 + 4);
      FragU f;
      f.u[0] = pkbf(a.x * qsA, a.y * qsA);
      f.u[1] = pkbf(a.z * qsA, a.w * qsA);
      f.u[2] = pkbf(b.x * qsA, b.y * qsA);
      f.u[3] = pkbf(b.z * qsA, b.w * qsA);
      qfA[c] = f.f;
    }
    const int growB = qbase + 32 + lq;
    const float qsB = mqg[batch * N_ + growB] ? 0.1803368801111204f : 0.0f;
    const float* QpB = qg + ((size_t)batch * N_ + growB) * D_ + lh * 8;
#pragma unroll
    for (int c = 0; c < 4; ++c) {
      float4 a = *(const float4*)(QpB + c * 16);
      float4 b = *(const float4*)(QpB + c * 16 + 4);
      FragU f;
      f.u[0] = pkbf(a.x * qsB, a.y * qsB);
      f.u[1] = pkbf(a.z * qsB, a.w * qsB);
      f.u[2] = pkbf(b.x * qsB, b.y * qsB);
      f.u[3] = pkbf(b.z * qsB, b.w * qsB);
      qfB[c] = f.f;
    }
  }
  __syncthreads();  // bias staged

  f32x16 oA0, oA1, oB0, oB1;
#pragma unroll
  for (int i = 0; i < 16; ++i) { oA0[i] = 0.f; oA1[i] = 0.f; oB0[i] = 0.f; oB1[i] = 0.f; }
  float lsumA = 0.f, lsumB = 0.f;

  const float* blw = (const float*)smem + wid * 1024;

  for (int t16 = 0; t16 < 16; ++t16) {
    const int tile = wid * 16 + t16;
    const size_t tb = (size_t)(batch * 64 + tile) * 8192 + (size_t)lane * 16;

    // ---- K + V frags (one load set feeds both q-groups) ----
    bfrag kf[4][2];
#pragma unroll
    for (int c = 0; c < 4; ++c) {
      kf[c][0] = *(const bfrag*)(kpack + tb + (c * 2 + 0) * 1024);
      kf[c][1] = *(const bfrag*)(kpack + tb + (c * 2 + 1) * 1024);
    }
    bfrag vf[4][2];
#pragma unroll
    for (int mc = 0; mc < 4; ++mc) {
      vf[mc][0] = *(const bfrag*)(vpack + tb + (mc * 2 + 0) * 1024);
      vf[mc][1] = *(const bfrag*)(vpack + tb + (mc * 2 + 1) * 1024);
    }

    // ---- swapped QK^T for both groups ----
    f32x16 sA0, sA1, sB0, sB1;
#pragma unroll
    for (int i = 0; i < 16; ++i) { sA0[i] = 0.f; sA1[i] = 0.f; sB0[i] = 0.f; sB1[i] = 0.f; }
    __builtin_amdgcn_s_setprio(1);
#pragma unroll
    for (int c = 0; c < 4; ++c) {
      sA0 = __builtin_amdgcn_mfma_f32_32x32x16_bf16(kf[c][0], qfA[c], sA0, 0, 0, 0);
      sA1 = __builtin_amdgcn_mfma_f32_32x32x16_bf16(kf[c][1], qfA[c], sA1, 0, 0, 0);
      sB0 = __builtin_amdgcn_mfma_f32_32x32x16_bf16(kf[c][0], qfB[c], sB0, 0, 0, 0);
      sB1 = __builtin_amdgcn_mfma_f32_32x32x16_bf16(kf[c][1], qfB[c], sB1, 0, 0, 0);
    }
    __builtin_amdgcn_s_setprio(0);

    // ---- softmax numerators (bias permuted to rows; no max: R7) ----
    const float* bb = blw + t16 * 64;
    f32x4 psvA = {0.f, 0.f, 0.f, 0.f}, psvB = {0.f, 0.f, 0.f, 0.f};
#pragma unroll
    for (int g = 0; g < 4; ++g) {
      f32x4 b0 = *(const f32x4*)(bb + g * 8 + 4 * lh);
      f32x4 b1 = *(const f32x4*)(bb + 32 + g * 8 + 4 * lh);
#pragma unroll
      for (int r = 0; r < 4; ++r) {
        float pA0 = __builtin_amdgcn_exp2f(sA0[g * 4 + r] + b0[r]);
        float pA1 = __builtin_amdgcn_exp2f(sA1[g * 4 + r] + b1[r]);
        float pB0 = __builtin_amdgcn_exp2f(sB0[g * 4 + r] + b0[r]);
        float pB1 = __builtin_amdgcn_exp2f(sB1[g * 4 + r] + b1[r]);
        sA0[g * 4 + r] = pA0; sA1[g * 4 + r] = pA1;
        sB0[g * 4 + r] = pB0; sB1[g * 4 + r] = pB1;
        psvA[r] += pA0 + pA1;
        psvB[r] += pB0 + pB1;
      }
    }
    lsumA += (psvA[0] + psvA[1]) + (psvA[2] + psvA[3]);
    lsumB += (psvB[0] + psvB[1]) + (psvB[2] + psvB[3]);

    // ---- P·V: A-frags are pure own-register repacks (key-permuted kpack) ----
#pragma unroll
    for (int mc = 0; mc < 4; ++mc) {
      const int Rb = (mc & 1) * 8;
      FragU pa;
      if (mc < 2) {
        pa.u[0] = pkbf(sA0[Rb + 0], sA0[Rb + 1]);
        pa.u[1] = pkbf(sA0[Rb + 2], sA0[Rb + 3]);
        pa.u[2] = pkbf(sA0[Rb + 4], sA0[Rb + 5]);
        pa.u[3] = pkbf(sA0[Rb + 6], sA0[Rb + 7]);
      } else {
        pa.u[0] = pkbf(sA1[Rb + 0], sA1[Rb + 1]);
        pa.u[1] = pkbf(sA1[Rb + 2], sA1[Rb + 3]);
        pa.u[2] = pkbf(sA1[Rb + 4], sA1[Rb + 5]);
        pa.u[3] = pkbf(sA1[Rb + 6], sA1[Rb + 7]);
      }
      __builtin_amdgcn_s_setprio(1);
      oA0 = __builtin_amdgcn_mfma_f32_32x32x16_bf16(pa.f, vf[mc][0], oA0, 0, 0, 0);
      oA1 = __builtin_amdgcn_mfma_f32_32x32x16_bf16(pa.f, vf[mc][1], oA1, 0, 0, 0);
      __builtin_amdgcn_s_setprio(0);
    }
#pragma unroll
    for (int mc = 0; mc < 4; ++mc) {
      const int Rb = (mc & 1) * 8;
      FragU pa;
      if (mc < 2) {
        pa.u[0] = pkbf(sB0[Rb + 0], sB0[Rb + 1]);
        pa.u[1] = pkbf(sB0[Rb + 2], sB0[Rb + 3]);
        pa.u[2] = pkbf(sB0[Rb + 4], sB0[Rb + 5]);
        pa.u[3] = pkbf(sB0[Rb + 6], sB0[Rb + 7]);
      } else {
        pa.u[0] = pkbf(sB1[Rb + 0], sB1[Rb + 1]);
        pa.u[1] = pkbf(sB1[Rb + 2], sB1[Rb + 3]);
        pa.u[2] = pkbf(sB1[Rb + 4], sB1[Rb + 5]);
        pa.u[3] = pkbf(sB1[Rb + 6], sB1[Rb + 7]);
      }
      __builtin_amdgcn_s_setprio(1);
      oB0 = __builtin_amdgcn_mfma_f32_32x32x16_bf16(pa.f, vf[mc][0], oB0, 0, 0, 0);
      oB1 = __builtin_amdgcn_mfma_f32_32x32x16_bf16(pa.f, vf[mc][1], oB1, 0, 0, 0);
      __builtin_amdgcn_s_setprio(0);
    }
  }

  // ---- deferred cross-half l reduce (once, not per tile) ----
  lsumA += __shfl_xor(lsumA, 32);
  lsumB += __shfl_xor(lsumB, 32);

  // ---- 4-way merge per group (linear: no max tracking) ----
  if (lane < 32) { lArrA[wid * 32 + lane] = lsumA; lArrB[wid * 32 + lane] = lsumB; }
  __syncthreads();
  {
    float ltA = 0.f, ltB = 0.f;
#pragma unroll
    for (int w = 0; w < 4; ++w) { ltA += lArrA[w * 32 + lq]; ltB += lArrB[w * 32 + lq]; }
    if (wid == 0 && lane < 32) { IlvA[lane] = 1.f / ltA; IlvB[lane] = 1.f / ltB; }
  }
  __syncthreads();
#pragma unroll
  for (int g = 0; g < 4; ++g) {
    f32x4 IvA = *(const f32x4*)(IlvA + g * 8 + 4 * lh);
    f32x4 IvB = *(const f32x4*)(IlvB + g * 8 + 4 * lh);
#pragma unroll
    for (int rr = 0; rr < 4; ++rr) {
      oA0[g * 4 + rr] *= IvA[rr];
      oA1[g * 4 + rr] *= IvA[rr];
      oB0[g * 4 + rr] *= IvB[rr];
      oB1[g * 4 + rr] *= IvB[rr];
    }
  }
  // accumulate: waves 0,1 write buf[wid]; waves 2,3 add into buf[wid-2]
  float* bufsA = (float*)smem;            // [2][32][64]
  float* bufsB = (float*)smem + 4096;     // [2][32][64]
  float* dA = bufsA + (wid & 1) * 2048;
  float* dB = bufsB + (wid & 1) * 2048;
  if (wid < 2) {
#pragma unroll
    for (int r = 0; r < 16; ++r) {
      const int row = (r & 3) + 8 * (r >> 2) + 4 * lh;
      dA[row * 64 + lq]      = oA0[r];
      dA[row * 64 + 32 + lq] = oA1[r];
      dB[row * 64 + lq]      = oB0[r];
      dB[row * 64 + 32 + lq] = oB1[r];
    }
  }
  __syncthreads();
  if (wid >= 2) {
#pragma unroll
    for (int r = 0; r < 16; ++r) {
      const int row = (r & 3) + 8 * (r >> 2) + 4 * lh;
      dA[row * 64 + lq]      += oA0[r];
      dA[row * 64 + 32 + lq] += oA1[r];
      dB[row * 64 + lq]      += oB0[r];
      dB[row * 64 + 32 + lq] += oB1[r];
    }
  }
  __syncthreads();
  // final: out rows [qbase, qbase+64) = bufX0 + bufX1, coalesced
  {
    float* op = outg + ((size_t)batch * N_ + qbase) * 64;
    const int i = tid * 8;
    f32x4 a0 = *(const f32x4*)(bufsA + i),     a1 = *(const f32x4*)(bufsA + 2048 + i);
    f32x4 b0 = *(const f32x4*)(bufsA + i + 4), b1 = *(const f32x4*)(bufsA + 2048 + i + 4);
#pragma unroll
    for (int r = 0; r < 4; ++r) { a0[r] += a1[r]; b0[r] += b1[r]; }
    *(f32x4*)(op + i)     = a0;
    *(f32x4*)(op + i + 4) = b0;
    f32x4 c0 = *(const f32x4*)(bufsB + i),     c1 = *(const f32x4*)(bufsB + 2048 + i);
    f32x4 d0 = *(const f32x4*)(bufsB + i + 4), d1 = *(const f32x4*)(bufsB + 2048 + i + 4);
#pragma unroll
    for (int r = 0; r < 4; ++r) { c0[r] += c1[r]; d0[r] += d1[r]; }
    *(f32x4*)(op + 2048 + i)     = c0;
    *(f32x4*)(op + 2048 + i + 4) = d0;
  }
}

// ---------------- fallback (R1, verified): used if ws too small ----------------
__device__ __forceinline__ unsigned int swz(unsigned int byte) {
  return byte ^ (((byte >> 7) & 7) << 4);
}

__global__ __launch_bounds__(256, 2) void attn_fused(
    const float* __restrict__ qg, const float* __restrict__ kg,
    const float* __restrict__ vg, const int* __restrict__ mqg,
    const int* __restrict__ mkg, float* __restrict__ outg)
{
  __shared__ alignas(16) char smem[35072];
  const int tid  = threadIdx.x;
  const int lane = tid & 63;
  const int lq   = lane & 31;
  const int lh   = lane >> 5;
  const int wid  = tid >> 6;
  const int khalf = wid >> 1;
  const int qrw  = (wid & 1) * 32;
  const int batch = blockIdx.x & 7;
  const int qbase = (blockIdx.x >> 3) * 64;

  char* Kl = smem + khalf * 8192;
  char* Vl = smem + 16384 + khalf * 8192;
  float* kbf    = (float*)(smem + 32768);
  float* alphav = (float*)(smem + 33280);
  float* mM     = (float*)(smem + 33792);
  float* mL     = (float*)(smem + 34048);
  float* bC0    = (float*)(smem + 34304);
  float* bC1    = (float*)(smem + 34560);

  const int grow = qbase + qrw + lq;
  const float qs = mqg[batch * N_ + grow] ? 0.1803368801111204f : 0.0f;
  bfrag qf[4];
  {
    const float* Qp = qg + ((size_t)batch * N_ + grow) * D_ + lh * 8;
#pragma unroll
    for (int c = 0; c < 4; ++c) {
      float4 a = *(const float4*)(Qp + c * 16);
      float4 b = *(const float4*)(Qp + c * 16 + 4);
      FragU f;
      f.u[0] = pkbf(a.x * qs, a.y * qs);
      f.u[1] = pkbf(a.z * qs, a.w * qs);
      f.u[2] = pkbf(b.x * qs, b.y * qs);
      f.u[3] = pkbf(b.z * qs, b.w * qs);
      qf[c] = f.f;
    }
  }

  const int sid   = tid & 127;
  const int shalf = tid >> 7;

  f32x16 o0, o1;
#pragma unroll
  for (int i = 0; i < 16; ++i) { o0[i] = 0.f; o1[i] = 0.f; }
  float m2 = -1e30f, lsum = 0.f;

  for (int t = 0; t < 32; ++t) {
    __syncthreads();
    {
      const int kb0 = shalf * 2048 + t * 64;
      const float4* K4 = (const float4*)(kg + ((size_t)batch * M_ + kb0) * D_);
      const float4* V4 = (const float4*)(vg + ((size_t)batch * M_ + kb0) * D_);
      char* Ks = smem + shalf * 8192;
      char* Vs = smem + 16384 + shalf * 8192;
#pragma unroll
      for (int j = 0; j < 8; ++j) {
        int idx = sid + j * 128;
        float4 a = K4[idx];
        int row = idx >> 4, col = (idx & 15) << 2;
        *(uint2*)(Ks + swz((unsigned)(row * 128 + col * 2))) =
            make_uint2(pkbf(a.x, a.y), pkbf(a.z, a.w));
        float4 b = V4[idx];
        int vk = idx >> 4, vc = (idx & 15) << 2;
        *(unsigned short*)(Vs + swz((unsigned)((vc + 0) * 128 + vk * 2))) = bf1(b.x);
        *(unsigned short*)(Vs + swz((unsigned)((vc + 1) * 128 + vk * 2))) = bf1(b.y);
        *(unsigned short*)(Vs + swz((unsigned)((vc + 2) * 128 + vk * 2))) = bf1(b.z);
        *(unsigned short*)(Vs + swz((unsigned)((vc + 3) * 128 + vk * 2))) = bf1(b.w);
      }
      if (sid < 64)
        kbf[shalf * 64 + sid] = mkg[batch * M_ + kb0 + sid] ? 0.f : -1e30f;
    }
    __syncthreads();

    f32x16 s0, s1;
#pragma unroll
    for (int i = 0; i < 16; ++i) { s0[i] = 0.f; s1[i] = 0.f; }
#pragma unroll
    for (int c = 0; c < 4; ++c) {
      bfrag kf0 = *(const bfrag*)(Kl + swz((unsigned)(lq * 128 + (c * 16 + lh * 8) * 2)));
      bfrag kf1 = *(const bfrag*)(Kl + swz((unsigned)((32 + lq) * 128 + (c * 16 + lh * 8) * 2)));
      s0 = __builtin_amdgcn_mfma_f32_32x32x16_bf16(kf0, qf[c], s0, 0, 0, 0);
      s1 = __builtin_amdgcn_mfma_f32_32x32x16_bf16(kf1, qf[c], s1, 0, 0, 0);
    }

    const float* kbh = kbf + khalf * 64;
    float mx = -1e30f;
#pragma unroll
    for (int g = 0; g < 4; ++g) {
      f32x4 b0 = *(const f32x4*)(kbh + g * 8 + 4 * lh);
      f32x4 b1 = *(const f32x4*)(kbh + 32 + g * 8 + 4 * lh);
#pragma unroll
      for (int r = 0; r < 4; ++r) {
        s0[g * 4 + r] += b0[r];
        s1[g * 4 + r] += b1[r];
        mx = fmaxf(mx, fmaxf(s0[g * 4 + r], s1[g * 4 + r]));
      }
    }
    mx = fmaxf(mx, __shfl_xor(mx, 32));

    if (__any(mx > m2 + 8.f)) {
      float mn = fmaxf(m2, mx);
      float al = __builtin_amdgcn_exp2f(m2 - mn);
      if (lane < 32) alphav[wid * 32 + lane] = al;
      asm volatile("s_waitcnt lgkmcnt(0)" ::: "memory");
#pragma unroll
      for (int g = 0; g < 4; ++g) {
        f32x4 av = *(const f32x4*)(alphav + wid * 32 + g * 8 + 4 * lh);
#pragma unroll
        for (int r = 0; r < 4; ++r) { o0[g * 4 + r] *= av[r]; o1[g * 4 + r] *= av[r]; }
      }
      lsum *= al;
      m2 = mn;
    }

    float ps = 0.f;
#pragma unroll
    for (int i = 0; i < 16; ++i) {
      float p0 = __builtin_amdgcn_exp2f(s0[i] - m2);
      float p1 = __builtin_amdgcn_exp2f(s1[i] - m2);
      s0[i] = p0; s1[i] = p1;
      ps += p0 + p1;
    }
    ps += __shfl_xor(ps, 32);
    lsum += ps;

#pragma unroll
    for (int mc = 0; mc < 4; ++mc) {
      unsigned int c01, c23, c45, c67;
      {
        const int Rb = (mc & 1) * 8;
        if (mc < 2) {
          c01 = pkbf(s0[Rb + 0], s0[Rb + 1]); c23 = pkbf(s0[Rb + 2], s0[Rb + 3]);
          c45 = pkbf(s0[Rb + 4], s0[Rb + 5]); c67 = pkbf(s0[Rb + 6], s0[Rb + 7]);
        } else {
          c01 = pkbf(s1[Rb + 0], s1[Rb + 1]); c23 = pkbf(s1[Rb + 2], s1[Rb + 3]);
          c45 = pkbf(s1[Rb + 4], s1[Rb + 5]); c67 = pkbf(s1[Rb + 6], s1[Rb + 7]);
        }
      }
      unsigned int t01 = (unsigned int)__shfl_xor((int)c01, 32);
      unsigned int t23 = (unsigned int)__shfl_xor((int)c23, 32);
      unsigned int t45 = (unsigned int)__shfl_xor((int)c45, 32);
      unsigned int t67 = (unsigned int)__shfl_xor((int)c67, 32);
      FragU pa;
      pa.u[0] = lh ? t45 : c01;
      pa.u[1] = lh ? t67 : c23;
      pa.u[2] = lh ? c45 : t01;
      pa.u[3] = lh ? c67 : t23;
      bfrag vf0 = *(const bfrag*)(Vl + swz((unsigned)(lq * 128 + (mc * 16 + lh * 8) * 2)));
      bfrag vf1 = *(const bfrag*)(Vl + swz((unsigned)((32 + lq) * 128 + (mc * 16 + lh * 8) * 2)));
      o0 = __builtin_amdgcn_mfma_f32_32x32x16_bf16(pa.f, vf0, o0, 0, 0, 0);
      o1 = __builtin_amdgcn_mfma_f32_32x32x16_bf16(pa.f, vf1, o1, 0, 0, 0);
    }
  }

  __syncthreads();
  float* Omg = (float*)smem;
  if (khalf == 1) {
    const int w = wid & 1;
    if (lane < 32) { mM[w * 32 + lane] = m2; mL[w * 32 + lane] = lsum; }
#pragma unroll
    for (int r = 0; r < 16; ++r) {
      const int row = (r & 3) + 8 * (r >> 2) + 4 * lh;
      Omg[w * 2048 + row * 64 + lq]      = o0[r];
      Omg[w * 2048 + row * 64 + 32 + lq] = o1[r];
    }
  }
  __syncthreads();
  if (khalf == 0) {
    const int w = wid & 1;
    float m1 = mM[w * 32 + lq], l1 = mL[w * 32 + lq];
    float msf = fmaxf(m2, m1);
    float c0 = __builtin_amdgcn_exp2f(m2 - msf);
    float c1 = __builtin_amdgcn_exp2f(m1 - msf);
    float il = 1.f / (lsum * c0 + l1 * c1);
    if (lane < 32) { bC0[w * 32 + lane] = c0 * il; bC1[w * 32 + lane] = c1 * il; }
    asm volatile("s_waitcnt lgkmcnt(0)" ::: "memory");
    float* outp = outg + ((size_t)batch * N_ + qbase + qrw) * 64;
#pragma unroll
    for (int g = 0; g < 4; ++g) {
      f32x4 a0 = *(const f32x4*)(bC0 + w * 32 + g * 8 + 4 * lh);
      f32x4 a1 = *(const f32x4*)(bC1 + w * 32 + g * 8 + 4 * lh);
#pragma unroll
      for (int rr = 0; rr < 4; ++rr) {
        const int r = g * 4 + rr;
        const int row = rr + 8 * g + 4 * lh;
        float r0 = o0[r] * a0[rr] + Omg[w * 2048 + row * 64 + lq]      * a1[rr];
        float r1 = o1[r] * a0[rr] + Omg[w * 2048 + row * 64 + 32 + lq] * a1[rr];
        outp[(size_t)row * 64 + lq]      = r0;
        outp[(size_t)row * 64 + 32 + lq] = r1;
      }
    }
  }
}

extern "C" void kernel_launch(void* const* d_in, const int* in_sizes, int n_in,
                              void* d_out, int out_size, void* d_ws, size_t ws_size,
                              hipStream_t stream) {
  const float* q  = (const float*)d_in[0];
  const float* k  = (const float*)d_in[1];
  const float* v  = (const float*)d_in[2];
  const int*   mq = (const int*)d_in[3];
  const int*   mk = (const int*)d_in[4];
  float* out = (float*)d_out;

  const size_t kp_off = 0;
  const size_t vp_off = (size_t)B_ * 64 * 8192;            // 4 MiB
  const size_t need   = vp_off * 2;                        // 8 MiB

  if (ws_size >= need) {
    char* kpack = (char*)d_ws + kp_off;
    char* vpack = (char*)d_ws + vp_off;
    attn_prepass<<<dim3(2048), dim3(256), 0, stream>>>(k, v, kpack, vpack);
    attn_main<<<dim3(512), dim3(256), 0, stream>>>(q, mq, mk, kpack, vpack, out);
  } else {
    attn_fused<<<dim3(512), dim3(256), 0, stream>>>(q, k, v, mq, mk, out);
  }
}

// Round 14
// 52.655 us; speedup vs baseline: 6.5766x; 1.0567x over previous
//
#include <hip/hip_runtime.h>

// Masked attention, b=8 n=m=4096 d=dv=64, f32 in/out.
// R14: R13 (key-permuted kpack, zero-shuffle PV) + mask folded into prepass:
// masked keys get ZEROED K and V rows (p=1 spurious, V=0 kills PV effect);
// lsum corrected by subtracting the wave's masked-key count (computed once in
// prologue). Deletes per-tile bias LDS reads + 32 VALU adds; K-loop is LDS-free.

#define B_ 8
#define N_ 4096
#define M_ 4096
#define D_ 64

typedef __attribute__((ext_vector_type(8))) __bf16 bfrag;
typedef __attribute__((ext_vector_type(16))) float f32x16;
typedef __attribute__((ext_vector_type(4))) float f32x4;

union FragU { bfrag f; unsigned int u[4]; };

__device__ __forceinline__ unsigned int pkbf(float lo, float hi) {
  unsigned short a = __builtin_bit_cast(unsigned short, (__bf16)lo);
  unsigned short b = __builtin_bit_cast(unsigned short, (__bf16)hi);
  return ((unsigned int)b << 16) | (unsigned int)a;
}
__device__ __forceinline__ unsigned short bf1(float x) {
  return __builtin_bit_cast(unsigned short, (__bf16)x);
}

// ---------------- prepass: pack fragment-order bf16 images ----------------
// kpack: key PERMUTED (swap bits 2<->3 of 32-row index) so QK^T C/D rows land
// where PV's A-operand wants them. Masked keys: K row and V row written as 0.
__global__ void attn_prepass(const float* __restrict__ kg, const float* __restrict__ vg,
                             const int* __restrict__ mkg,
                             char* __restrict__ kpack, char* __restrict__ vpack)
{
  const int bid = blockIdx.x, tid = threadIdx.x;
  if (bid < 1024) {
    const unsigned c0 = bid * 256 + tid;     // 0..262143
    const int lane = c0 & 63;
    const unsigned u = c0 >> 6;
    const int f = u & 1, c = (u >> 1) & 3, tile = (u >> 3) & 63, batch = u >> 9;
    const int lq = lane & 31, lh = lane >> 5;
    const int lqp = (lq & 19) | ((lq & 4) << 1) | ((lq & 8) >> 1);  // swap bits 2,3
    const int row = tile * 64 + f * 32 + lqp;
    const float sc = mkg[batch * M_ + row] ? 1.f : 0.f;
    const float* src = kg + (((size_t)batch * M_ + row) * D_ + c * 16 + lh * 8);
    float4 a = ((const float4*)src)[0], b = ((const float4*)src)[1];
    uint4 o;
    o.x = pkbf(a.x * sc, a.y * sc); o.y = pkbf(a.z * sc, a.w * sc);
    o.z = pkbf(b.x * sc, b.y * sc); o.w = pkbf(b.z * sc, b.w * sc);
    *(uint4*)(kpack + (size_t)c0 * 16) = o;
  } else {
    const unsigned c0 = (bid - 1024) * 256 + tid;
    const int lane = c0 & 63;
    const unsigned u = c0 >> 6;
    const int f = u & 1, mc = (u >> 1) & 3, tile = (u >> 3) & 63, batch = u >> 9;
    const int lq = lane & 31, lh = lane >> 5;
    const int key0 = tile * 64 + mc * 16 + lh * 8;
    const int dv = f * 32 + lq;
    const float* base = vg + (((size_t)batch * M_ + key0) * D_ + dv);
    const int* mkp = mkg + batch * M_ + key0;
    int4 ma = *(const int4*)(mkp);
    int4 mb = *(const int4*)(mkp + 4);
    unsigned short h[8];
    h[0] = ma.x ? bf1(base[0 * D_]) : (unsigned short)0;
    h[1] = ma.y ? bf1(base[1 * D_]) : (unsigned short)0;
    h[2] = ma.z ? bf1(base[2 * D_]) : (unsigned short)0;
    h[3] = ma.w ? bf1(base[3 * D_]) : (unsigned short)0;
    h[4] = mb.x ? bf1(base[4 * D_]) : (unsigned short)0;
    h[5] = mb.y ? bf1(base[5 * D_]) : (unsigned short)0;
    h[6] = mb.z ? bf1(base[6 * D_]) : (unsigned short)0;
    h[7] = mb.w ? bf1(base[7 * D_]) : (unsigned short)0;
    uint4 o;
    o.x = (unsigned)h[0] | ((unsigned)h[1] << 16);
    o.y = (unsigned)h[2] | ((unsigned)h[3] << 16);
    o.z = (unsigned)h[4] | ((unsigned)h[5] << 16);
    o.w = (unsigned)h[6] | ((unsigned)h[7] << 16);
    *(uint4*)(vpack + (size_t)c0 * 16) = o;
  }
}

// ---------------- main kernel: 256 thr, 4-way key split, QBLK=64/wave --------
// K-loop is LDS-free. LDS only for epilogue:
//   bufsA [2][32][64] f32 @0 (16KB); bufsB @16384 (16KB);
//   32768 lArrA[4][32]; 33280 lArrB[4][32]; 33792 IlvA[32]; 33920 IlvB[32]
__global__ __launch_bounds__(256, 2) void attn_main(
    const float* __restrict__ qg, const int* __restrict__ mqg,
    const int* __restrict__ mkg, const char* __restrict__ kpack,
    const char* __restrict__ vpack, float* __restrict__ outg)
{
  __shared__ alignas(16) char smem[34048];
  const int tid  = threadIdx.x;
  const int lane = tid & 63;
  const int lq   = lane & 31;
  const int lh   = lane >> 5;
  const int wid  = tid >> 6;            // key quarter, 0..3
  const int batch = blockIdx.x & 7;     // batch == XCD for L2 locality
  const int qbase = (blockIdx.x >> 3) * 64;

  float* lArrA = (float*)(smem + 32768);
  float* lArrB = (float*)(smem + 33280);
  float* IlvA  = (float*)(smem + 33792);
  float* IlvB  = (float*)(smem + 33920);

  // ---- masked-key count for this wave's 1024-key quarter (wave-uniform) ----
  int cnt = 0;
  {
    const int* mkp = mkg + batch * M_ + wid * 1024;
#pragma unroll
    for (int j = 0; j < 16; ++j) cnt += (mkp[j * 64 + lane] == 0);
#pragma unroll
    for (int off = 32; off >= 1; off >>= 1) cnt += __shfl_xor(cnt, off);
  }
  const float cntf = (float)cnt;

  // ---- Q frags for both 32-row groups (A: rows +lq, B: rows +32+lq) ----
  bfrag qfA[4], qfB[4];
  {
    const int growA = qbase + lq;
    const float qsA = mqg[batch * N_ + growA] ? 0.1803368801111204f : 0.0f;
    const float* QpA = qg + ((size_t)batch * N_ + growA) * D_ + lh * 8;
#pragma unroll
    for (int c = 0; c < 4; ++c) {
      float4 a = *(const float4*)(QpA + c * 16);
      float4 b = *(const float4*)(QpA + c * 16 + 4);
      FragU f;
      f.u[0] = pkbf(a.x * qsA, a.y * qsA);
      f.u[1] = pkbf(a.z * qsA, a.w * qsA);
      f.u[2] = pkbf(b.x * qsA, b.y * qsA);
      f.u[3] = pkbf(b.z * qsA, b.w * qsA);
      qfA[c] = f.f;
    }
    const int growB = qbase + 32 + lq;
    const float qsB = mqg[batch * N_ + growB] ? 0.1803368801111204f : 0.0f;
    const float* QpB = qg + ((size_t)batch * N_ + growB) * D_ + lh * 8;
#pragma unroll
    for (int c = 0; c < 4; ++c) {
      float4 a = *(const float4*)(QpB + c * 16);
      float4 b = *(const float4*)(QpB + c * 16 + 4);
      FragU f;
      f.u[0] = pkbf(a.x * qsB, a.y * qsB);
      f.u[1] = pkbf(a.z * qsB, a.w * qsB);
      f.u[2] = pkbf(b.x * qsB, b.y * qsB);
      f.u[3] = pkbf(b.z * qsB, b.w * qsB);
      qfB[c] = f.f;
    }
  }

  f32x16 oA0, oA1, oB0, oB1;
#pragma unroll
  for (int i = 0; i < 16; ++i) { oA0[i] = 0.f; oA1[i] = 0.f; oB0[i] = 0.f; oB1[i] = 0.f; }
  float lsumA = 0.f, lsumB = 0.f;

  for (int t16 = 0; t16 < 16; ++t16) {
    const int tile = wid * 16 + t16;
    const size_t tb = (size_t)(batch * 64 + tile) * 8192 + (size_t)lane * 16;

    // ---- K + V frags (one load set feeds both q-groups) ----
    bfrag kf[4][2];
#pragma unroll
    for (int c = 0; c < 4; ++c) {
      kf[c][0] = *(const bfrag*)(kpack + tb + (c * 2 + 0) * 1024);
      kf[c][1] = *(const bfrag*)(kpack + tb + (c * 2 + 1) * 1024);
    }
    bfrag vf[4][2];
#pragma unroll
    for (int mc = 0; mc < 4; ++mc) {
      vf[mc][0] = *(const bfrag*)(vpack + tb + (mc * 2 + 0) * 1024);
      vf[mc][1] = *(const bfrag*)(vpack + tb + (mc * 2 + 1) * 1024);
    }

    // ---- swapped QK^T for both groups ----
    f32x16 sA0, sA1, sB0, sB1;
#pragma unroll
    for (int i = 0; i < 16; ++i) { sA0[i] = 0.f; sA1[i] = 0.f; sB0[i] = 0.f; sB1[i] = 0.f; }
    __builtin_amdgcn_s_setprio(1);
#pragma unroll
    for (int c = 0; c < 4; ++c) {
      sA0 = __builtin_amdgcn_mfma_f32_32x32x16_bf16(kf[c][0], qfA[c], sA0, 0, 0, 0);
      sA1 = __builtin_amdgcn_mfma_f32_32x32x16_bf16(kf[c][1], qfA[c], sA1, 0, 0, 0);
      sB0 = __builtin_amdgcn_mfma_f32_32x32x16_bf16(kf[c][0], qfB[c], sB0, 0, 0, 0);
      sB1 = __builtin_amdgcn_mfma_f32_32x32x16_bf16(kf[c][1], qfB[c], sB1, 0, 0, 0);
    }
    __builtin_amdgcn_s_setprio(0);

    // ---- p = exp2(s) (mask already folded into K/V; no bias, no max) ----
    f32x4 psvA = {0.f, 0.f, 0.f, 0.f}, psvB = {0.f, 0.f, 0.f, 0.f};
#pragma unroll
    for (int g = 0; g < 4; ++g) {
#pragma unroll
      for (int r = 0; r < 4; ++r) {
        float pA0 = __builtin_amdgcn_exp2f(sA0[g * 4 + r]);
        float pA1 = __builtin_amdgcn_exp2f(sA1[g * 4 + r]);
        float pB0 = __builtin_amdgcn_exp2f(sB0[g * 4 + r]);
        float pB1 = __builtin_amdgcn_exp2f(sB1[g * 4 + r]);
        sA0[g * 4 + r] = pA0; sA1[g * 4 + r] = pA1;
        sB0[g * 4 + r] = pB0; sB1[g * 4 + r] = pB1;
        psvA[r] += pA0 + pA1;
        psvB[r] += pB0 + pB1;
      }
    }
    lsumA += (psvA[0] + psvA[1]) + (psvA[2] + psvA[3]);
    lsumB += (psvB[0] + psvB[1]) + (psvB[2] + psvB[3]);

    // ---- P·V: A-frags are pure own-register repacks (key-permuted kpack) ----
#pragma unroll
    for (int mc = 0; mc < 4; ++mc) {
      const int Rb = (mc & 1) * 8;
      FragU pa;
      if (mc < 2) {
        pa.u[0] = pkbf(sA0[Rb + 0], sA0[Rb + 1]);
        pa.u[1] = pkbf(sA0[Rb + 2], sA0[Rb + 3]);
        pa.u[2] = pkbf(sA0[Rb + 4], sA0[Rb + 5]);
        pa.u[3] = pkbf(sA0[Rb + 6], sA0[Rb + 7]);
      } else {
        pa.u[0] = pkbf(sA1[Rb + 0], sA1[Rb + 1]);
        pa.u[1] = pkbf(sA1[Rb + 2], sA1[Rb + 3]);
        pa.u[2] = pkbf(sA1[Rb + 4], sA1[Rb + 5]);
        pa.u[3] = pkbf(sA1[Rb + 6], sA1[Rb + 7]);
      }
      __builtin_amdgcn_s_setprio(1);
      oA0 = __builtin_amdgcn_mfma_f32_32x32x16_bf16(pa.f, vf[mc][0], oA0, 0, 0, 0);
      oA1 = __builtin_amdgcn_mfma_f32_32x32x16_bf16(pa.f, vf[mc][1], oA1, 0, 0, 0);
      __builtin_amdgcn_s_setprio(0);
    }
#pragma unroll
    for (int mc = 0; mc < 4; ++mc) {
      const int Rb = (mc & 1) * 8;
      FragU pa;
      if (mc < 2) {
        pa.u[0] = pkbf(sB0[Rb + 0], sB0[Rb + 1]);
        pa.u[1] = pkbf(sB0[Rb + 2], sB0[Rb + 3]);
        pa.u[2] = pkbf(sB0[Rb + 4], sB0[Rb + 5]);
        pa.u[3] = pkbf(sB0[Rb + 6], sB0[Rb + 7]);
      } else {
        pa.u[0] = pkbf(sB1[Rb + 0], sB1[Rb + 1]);
        pa.u[1] = pkbf(sB1[Rb + 2], sB1[Rb + 3]);
        pa.u[2] = pkbf(sB1[Rb + 4], sB1[Rb + 5]);
        pa.u[3] = pkbf(sB1[Rb + 6], sB1[Rb + 7]);
      }
      __builtin_amdgcn_s_setprio(1);
      oB0 = __builtin_amdgcn_mfma_f32_32x32x16_bf16(pa.f, vf[mc][0], oB0, 0, 0, 0);
      oB1 = __builtin_amdgcn_mfma_f32_32x32x16_bf16(pa.f, vf[mc][1], oB1, 0, 0, 0);
      __builtin_amdgcn_s_setprio(0);
    }
  }

  // ---- cross-half l reduce, then subtract the spurious masked-key ones ----
  lsumA += __shfl_xor(lsumA, 32);
  lsumB += __shfl_xor(lsumB, 32);
  lsumA -= cntf;
  lsumB -= cntf;

  // ---- 4-way merge per group ----
  if (lane < 32) { lArrA[wid * 32 + lane] = lsumA; lArrB[wid * 32 + lane] = lsumB; }
  __syncthreads();
  {
    float ltA = 0.f, ltB = 0.f;
#pragma unroll
    for (int w = 0; w < 4; ++w) { ltA += lArrA[w * 32 + lq]; ltB += lArrB[w * 32 + lq]; }
    if (wid == 0 && lane < 32) { IlvA[lane] = 1.f / ltA; IlvB[lane] = 1.f / ltB; }
  }
  __syncthreads();
#pragma unroll
  for (int g = 0; g < 4; ++g) {
    f32x4 IvA = *(const f32x4*)(IlvA + g * 8 + 4 * lh);
    f32x4 IvB = *(const f32x4*)(IlvB + g * 8 + 4 * lh);
#pragma unroll
    for (int rr = 0; rr < 4; ++rr) {
      oA0[g * 4 + rr] *= IvA[rr];
      oA1[g * 4 + rr] *= IvA[rr];
      oB0[g * 4 + rr] *= IvB[rr];
      oB1[g * 4 + rr] *= IvB[rr];
    }
  }
  // accumulate: waves 0,1 write buf[wid]; waves 2,3 add into buf[wid-2]
  float* bufsA = (float*)smem;            // [2][32][64]
  float* bufsB = (float*)smem + 4096;     // [2][32][64]
  float* dA = bufsA + (wid & 1) * 2048;
  float* dB = bufsB + (wid & 1) * 2048;
  if (wid < 2) {
#pragma unroll
    for (int r = 0; r < 16; ++r) {
      const int row = (r & 3) + 8 * (r >> 2) + 4 * lh;
      dA[row * 64 + lq]      = oA0[r];
      dA[row * 64 + 32 + lq] = oA1[r];
      dB[row * 64 + lq]      = oB0[r];
      dB[row * 64 + 32 + lq] = oB1[r];
    }
  }
  __syncthreads();
  if (wid >= 2) {
#pragma unroll
    for (int r = 0; r < 16; ++r) {
      const int row = (r & 3) + 8 * (r >> 2) + 4 * lh;
      dA[row * 64 + lq]      += oA0[r];
      dA[row * 64 + 32 + lq] += oA1[r];
      dB[row * 64 + lq]      += oB0[r];
      dB[row * 64 + 32 + lq] += oB1[r];
    }
  }
  __syncthreads();
  // final: out rows [qbase, qbase+64) = bufX0 + bufX1, coalesced
  {
    float* op = outg + ((size_t)batch * N_ + qbase) * 64;
    const int i = tid * 8;
    f32x4 a0 = *(const f32x4*)(bufsA + i),     a1 = *(const f32x4*)(bufsA + 2048 + i);
    f32x4 b0 = *(const f32x4*)(bufsA + i + 4), b1 = *(const f32x4*)(bufsA + 2048 + i + 4);
#pragma unroll
    for (int r = 0; r < 4; ++r) { a0[r] += a1[r]; b0[r] += b1[r]; }
    *(f32x4*)(op + i)     = a0;
    *(f32x4*)(op + i + 4) = b0;
    f32x4 c0 = *(const f32x4*)(bufsB + i),     c1 = *(const f32x4*)(bufsB + 2048 + i);
    f32x4 d0 = *(const f32x4*)(bufsB + i + 4), d1 = *(const f32x4*)(bufsB + 2048 + i + 4);
#pragma unroll
    for (int r = 0; r < 4; ++r) { c0[r] += c1[r]; d0[r] += d1[r]; }
    *(f32x4*)(op + 2048 + i)     = c0;
    *(f32x4*)(op + 2048 + i + 4) = d0;
  }
}

// ---------------- fallback (R1, verified): used if ws too small ----------------
__device__ __forceinline__ unsigned int swz(unsigned int byte) {
  return byte ^ (((byte >> 7) & 7) << 4);
}

__global__ __launch_bounds__(256, 2) void attn_fused(
    const float* __restrict__ qg, const float* __restrict__ kg,
    const float* __restrict__ vg, const int* __restrict__ mqg,
    const int* __restrict__ mkg, float* __restrict__ outg)
{
  __shared__ alignas(16) char smem[35072];
  const int tid  = threadIdx.x;
  const int lane = tid & 63;
  const int lq   = lane & 31;
  const int lh   = lane >> 5;
  const int wid  = tid >> 6;
  const int khalf = wid >> 1;
  const int qrw  = (wid & 1) * 32;
  const int batch = blockIdx.x & 7;
  const int qbase = (blockIdx.x >> 3) * 64;

  char* Kl = smem + khalf * 8192;
  char* Vl = smem + 16384 + khalf * 8192;
  float* kbf    = (float*)(smem + 32768);
  float* alphav = (float*)(smem + 33280);
  float* mM     = (float*)(smem + 33792);
  float* mL     = (float*)(smem + 34048);
  float* bC0    = (float*)(smem + 34304);
  float* bC1    = (float*)(smem + 34560);

  const int grow = qbase + qrw + lq;
  const float qs = mqg[batch * N_ + grow] ? 0.1803368801111204f : 0.0f;
  bfrag qf[4];
  {
    const float* Qp = qg + ((size_t)batch * N_ + grow) * D_ + lh * 8;
#pragma unroll
    for (int c = 0; c < 4; ++c) {
      float4 a = *(const float4*)(Qp + c * 16);
      float4 b = *(const float4*)(Qp + c * 16 + 4);
      FragU f;
      f.u[0] = pkbf(a.x * qs, a.y * qs);
      f.u[1] = pkbf(a.z * qs, a.w * qs);
      f.u[2] = pkbf(b.x * qs, b.y * qs);
      f.u[3] = pkbf(b.z * qs, b.w * qs);
      qf[c] = f.f;
    }
  }

  const int sid   = tid & 127;
  const int shalf = tid >> 7;

  f32x16 o0, o1;
#pragma unroll
  for (int i = 0; i < 16; ++i) { o0[i] = 0.f; o1[i] = 0.f; }
  float m2 = -1e30f, lsum = 0.f;

  for (int t = 0; t < 32; ++t) {
    __syncthreads();
    {
      const int kb0 = shalf * 2048 + t * 64;
      const float4* K4 = (const float4*)(kg + ((size_t)batch * M_ + kb0) * D_);
      const float4* V4 = (const float4*)(vg + ((size_t)batch * M_ + kb0) * D_);
      char* Ks = smem + shalf * 8192;
      char* Vs = smem + 16384 + shalf * 8192;
#pragma unroll
      for (int j = 0; j < 8; ++j) {
        int idx = sid + j * 128;
        float4 a = K4[idx];
        int row = idx >> 4, col = (idx & 15) << 2;
        *(uint2*)(Ks + swz((unsigned)(row * 128 + col * 2))) =
            make_uint2(pkbf(a.x, a.y), pkbf(a.z, a.w));
        float4 b = V4[idx];
        int vk = idx >> 4, vc = (idx & 15) << 2;
        *(unsigned short*)(Vs + swz((unsigned)((vc + 0) * 128 + vk * 2))) = bf1(b.x);
        *(unsigned short*)(Vs + swz((unsigned)((vc + 1) * 128 + vk * 2))) = bf1(b.y);
        *(unsigned short*)(Vs + swz((unsigned)((vc + 2) * 128 + vk * 2))) = bf1(b.z);
        *(unsigned short*)(Vs + swz((unsigned)((vc + 3) * 128 + vk * 2))) = bf1(b.w);
      }
      if (sid < 64)
        kbf[shalf * 64 + sid] = mkg[batch * M_ + kb0 + sid] ? 0.f : -1e30f;
    }
    __syncthreads();

    f32x16 s0, s1;
#pragma unroll
    for (int i = 0; i < 16; ++i) { s0[i] = 0.f; s1[i] = 0.f; }
#pragma unroll
    for (int c = 0; c < 4; ++c) {
      bfrag kf0 = *(const bfrag*)(Kl + swz((unsigned)(lq * 128 + (c * 16 + lh * 8) * 2)));
      bfrag kf1 = *(const bfrag*)(Kl + swz((unsigned)((32 + lq) * 128 + (c * 16 + lh * 8) * 2)));
      s0 = __builtin_amdgcn_mfma_f32_32x32x16_bf16(kf0, qf[c], s0, 0, 0, 0);
      s1 = __builtin_amdgcn_mfma_f32_32x32x16_bf16(kf1, qf[c], s1, 0, 0, 0);
    }

    const float* kbh = kbf + khalf * 64;
    float mx = -1e30f;
#pragma unroll
    for (int g = 0; g < 4; ++g) {
      f32x4 b0 = *(const f32x4*)(kbh + g * 8 + 4 * lh);
      f32x4 b1 = *(const f32x4*)(kbh + 32 + g * 8 + 4 * lh);
#pragma unroll
      for (int r = 0; r < 4; ++r) {
        s0[g * 4 + r] += b0[r];
        s1[g * 4 + r] += b1[r];
        mx = fmaxf(mx, fmaxf(s0[g * 4 + r], s1[g * 4 + r]));
      }
    }
    mx = fmaxf(mx, __shfl_xor(mx, 32));

    if (__any(mx > m2 + 8.f)) {
      float mn = fmaxf(m2, mx);
      float al = __builtin_amdgcn_exp2f(m2 - mn);
      if (lane < 32) alphav[wid * 32 + lane] = al;
      asm volatile("s_waitcnt lgkmcnt(0)" ::: "memory");
#pragma unroll
      for (int g = 0; g < 4; ++g) {
        f32x4 av = *(const f32x4*)(alphav + wid * 32 + g * 8 + 4 * lh);
#pragma unroll
        for (int r = 0; r < 4; ++r) { o0[g * 4 + r] *= av[r]; o1[g * 4 + r] *= av[r]; }
      }
      lsum *= al;
      m2 = mn;
    }

    float ps = 0.f;
#pragma unroll
    for (int i = 0; i < 16; ++i) {
      float p0 = __builtin_amdgcn_exp2f(s0[i] - m2);
      float p1 = __builtin_amdgcn_exp2f(s1[i] - m2);
      s0[i] = p0; s1[i] = p1;
      ps += p0 + p1;
    }
    ps += __shfl_xor(ps, 32);
    lsum += ps;

#pragma unroll
    for (int mc = 0; mc < 4; ++mc) {
      unsigned int c01, c23, c45, c67;
      {
        const int Rb = (mc & 1) * 8;
        if (mc < 2) {
          c01 = pkbf(s0[Rb + 0], s0[Rb + 1]); c23 = pkbf(s0[Rb + 2], s0[Rb + 3]);
          c45 = pkbf(s0[Rb + 4], s0[Rb + 5]); c67 = pkbf(s0[Rb + 6], s0[Rb + 7]);
        } else {
          c01 = pkbf(s1[Rb + 0], s1[Rb + 1]); c23 = pkbf(s1[Rb + 2], s1[Rb + 3]);
          c45 = pkbf(s1[Rb + 4], s1[Rb + 5]); c67 = pkbf(s1[Rb + 6], s1[Rb + 7]);
        }
      }
      unsigned int t01 = (unsigned int)__shfl_xor((int)c01, 32);
      unsigned int t23 = (unsigned int)__shfl_xor((int)c23, 32);
      unsigned int t45 = (unsigned int)__shfl_xor((int)c45, 32);
      unsigned int t67 = (unsigned int)__shfl_xor((int)c67, 32);
      FragU pa;
      pa.u[0] = lh ? t45 : c01;
      pa.u[1] = lh ? t67 : c23;
      pa.u[2] = lh ? c45 : t01;
      pa.u[3] = lh ? c67 : t23;
      bfrag vf0 = *(const bfrag*)(Vl + swz((unsigned)(lq * 128 + (mc * 16 + lh * 8) * 2)));
      bfrag vf1 = *(const bfrag*)(Vl + swz((unsigned)((32 + lq) * 128 + (mc * 16 + lh * 8) * 2)));
      o0 = __builtin_amdgcn_mfma_f32_32x32x16_bf16(pa.f, vf0, o0, 0, 0, 0);
      o1 = __builtin_amdgcn_mfma_f32_32x32x16_bf16(pa.f, vf1, o1, 0, 0, 0);
    }
  }

  __syncthreads();
  float* Omg = (float*)smem;
  if (khalf == 1) {
    const int w = wid & 1;
    if (lane < 32) { mM[w * 32 + lane] = m2; mL[w * 32 + lane] = lsum; }
#pragma unroll
    for (int r = 0; r < 16; ++r) {
      const int row = (r & 3) + 8 * (r >> 2) + 4 * lh;
      Omg[w * 2048 + row * 64 + lq]      = o0[r];
      Omg[w * 2048 + row * 64 + 32 + lq] = o1[r];
    }
  }
  __syncthreads();
  if (khalf == 0) {
    const int w = wid & 1;
    float m1 = mM[w * 32 + lq], l1 = mL[w * 32 + lq];
    float msf = fmaxf(m2, m1);
    float c0 = __builtin_amdgcn_exp2f(m2 - msf);
    float c1 = __builtin_amdgcn_exp2f(m1 - msf);
    float il = 1.f / (lsum * c0 + l1 * c1);
    if (lane < 32) { bC0[w * 32 + lane] = c0 * il; bC1[w * 32 + lane] = c1 * il; }
    asm volatile("s_waitcnt lgkmcnt(0)" ::: "memory");
    float* outp = outg + ((size_t)batch * N_ + qbase + qrw) * 64;
#pragma unroll
    for (int g = 0; g < 4; ++g) {
      f32x4 a0 = *(const f32x4*)(bC0 + w * 32 + g * 8 + 4 * lh);
      f32x4 a1 = *(const f32x4*)(bC1 + w * 32 + g * 8 + 4 * lh);
#pragma unroll
      for (int rr = 0; rr < 4; ++rr) {
        const int r = g * 4 + rr;
        const int row = rr + 8 * g + 4 * lh;
        float r0 = o0[r] * a0[rr] + Omg[w * 2048 + row * 64 + lq]      * a1[rr];
        float r1 = o1[r] * a0[rr] + Omg[w * 2048 + row * 64 + 32 + lq] * a1[rr];
        outp[(size_t)row * 64 + lq]      = r0;
        outp[(size_t)row * 64 + 32 + lq] = r1;
      }
    }
  }
}

extern "C" void kernel_launch(void* const* d_in, const int* in_sizes, int n_in,
                              void* d_out, int out_size, void* d_ws, size_t ws_size,
                              hipStream_t stream) {
  const float* q  = (const float*)d_in[0];
  const float* k  = (const float*)d_in[1];
  const float* v  = (const float*)d_in[2];
  const int*   mq = (const int*)d_in[3];
  const int*   mk = (const int*)d_in[4];
  float* out = (float*)d_out;

  const size_t kp_off = 0;
  const size_t vp_off = (size_t)B_ * 64 * 8192;            // 4 MiB
  const size_t need   = vp_off * 2;                        // 8 MiB

  if (ws_size >= need) {
    char* kpack = (char*)d_ws + kp_off;
    char* vpack = (char*)d_ws + vp_off;
    attn_prepass<<<dim3(2048), dim3(256), 0, stream>>>(k, v, mk, kpack, vpack);
    attn_main<<<dim3(512), dim3(256), 0, stream>>>(q, mq, mk, kpack, vpack, out);
  } else {
    attn_fused<<<dim3(512), dim3(256), 0, stream>>>(q, k, v, mq, mk, out);
  }
}